// Round 12
// baseline (215.224 us; speedup 1.0000x reference)
//
#include <hip/hip_runtime.h>
#include <hip/hip_bf16.h>
#include <cstdint>
#include <cstddef>

#define LL 4096
#define BB 4
#define DD 1024
#define HH 16
#define PP 256
#define HDD 64
#define LC 16
#define LCHUNK 256

constexpr float kScaling = 0.125f;   // HD^-0.5
constexpr float kEps = 1e-5f;

typedef __attribute__((ext_vector_type(8))) short bf16x8;   // 8 bf16 = 4 VGPR
typedef __attribute__((ext_vector_type(4))) short short4v;
typedef __attribute__((ext_vector_type(4))) float f32x4;

#define MFMA16(a, b, c) __builtin_amdgcn_mfma_f32_16x16x32_bf16((a), (b), (c), 0, 0, 0)

__device__ __forceinline__ unsigned short f2bf(float f) {
  unsigned int u = __builtin_bit_cast(unsigned int, f);
  u += 0x7FFFu + ((u >> 16) & 1u);           // round-to-nearest-even
  return (unsigned short)(u >> 16);
}
__device__ __forceinline__ float bf2f(unsigned short u) {
  return __builtin_bit_cast(float, ((unsigned int)u) << 16);
}

__device__ __forceinline__ void gll16(const void* g, void* l) {
  __builtin_amdgcn_global_load_lds(
      (const __attribute__((address_space(1))) unsigned int*)g,
      (__attribute__((address_space(3))) unsigned int*)l, 16, 0, 0);
}

// ---------------------------------------------------------------------------
// Weights-only fp32 -> bf16 convert.
// ---------------------------------------------------------------------------
__global__ __launch_bounds__(256) void k_cvt_w(
    const float* __restrict__ w0, const float* __restrict__ w1,
    const float* __restrict__ w2, const float* __restrict__ w3,
    const float* __restrict__ w4, const float* __restrict__ w5,
    unsigned short* __restrict__ d0, unsigned short* __restrict__ d1,
    unsigned short* __restrict__ d2, unsigned short* __restrict__ d3,
    unsigned short* __restrict__ d4, unsigned short* __restrict__ d5) {
  int i = blockIdx.x * 256 + threadIdx.x;
  int w = i >> 17, off = i & 131071;
  const float* src; unsigned short* dst;
  if (w == 0) { src = w0; dst = d0; }
  else if (w == 1) { src = w1; dst = d1; }
  else if (w == 2) { src = w2; dst = d2; }
  else if (w == 3) { src = w3; dst = d3; }
  else if (w == 4) { src = w4; dst = d4; }
  else { if (off >= 32768) return; src = w5; dst = d5; }
  const float4* s = (const float4*)(src + (size_t)off * 8);
  float4 a = s[0], b = s[1];
  bf16x8 o;
  o[0] = f2bf(a.x); o[1] = f2bf(a.y); o[2] = f2bf(a.z); o[3] = f2bf(a.w);
  o[4] = f2bf(b.x); o[5] = f2bf(b.y); o[6] = f2bf(b.z); o[7] = f2bf(b.w);
  *(bf16x8*)(dst + (size_t)off * 8) = o;
}

// ---------------------------------------------------------------------------
// Compress (MFMA) + inline query cvt. T14 prefetch: next tile's query loaded
// into regs during current tile's compute; raw s_barrier (no vmcnt drain).
// ---------------------------------------------------------------------------
__global__ __launch_bounds__(256) void k_compress_mfma(
    const float* __restrict__ q32, const unsigned short* __restrict__ ewbf,
    unsigned short* __restrict__ qbf_out, unsigned short* __restrict__ parts) {
  const int bh = blockIdx.x, lc = blockIdx.y;
  const int b = bh >> 4, h = bh & 15;
  const int tid = threadIdx.x, wv = tid >> 6, lane = tid & 63;
  const int fr = lane & 15, fg = lane >> 4;

  __shared__ __align__(16) char Xl[8192];    // [l][d] rows of 128B
  __shared__ __align__(16) char Xtl[8192];   // [d][l]
  __shared__ __align__(16) char Pl[32768];   // [p][l] rows of 128B

  bf16x8 ef[4][2];
#pragma unroll
  for (int pt = 0; pt < 4; ++pt)
#pragma unroll
    for (int kc = 0; kc < 2; ++kc)
      ef[pt][kc] = *(const bf16x8*)(ewbf +
          (size_t)((h * PP + wv * 64 + pt * 16 + fr) * HDD) + kc * 32 + fg * 8);

  f32x4 acc[4][4];
#pragma unroll
  for (int i = 0; i < 4; ++i)
#pragma unroll
    for (int j = 0; j < 4; ++j) acc[i][j] = (f32x4){0.f, 0.f, 0.f, 0.f};

  const int l0 = lc * LCHUNK;
  const int l2 = tid >> 3, c8 = tid & 7;
  const int lp = 2 * l2;

  // prologue: tile 0 query -> regs
  float4 cur0, cur1, cur2, cur3;
  {
    const float* xp = q32 + ((size_t)(l0 + lp) * BB + b) * DD + h * HDD + c8 * 8;
    cur0 = *(const float4*)xp;       cur1 = *(const float4*)(xp + 4);
    cur2 = *(const float4*)(xp + BB * DD); cur3 = *(const float4*)(xp + BB * DD + 4);
  }

#pragma unroll
  for (int t = 0; t < 4; ++t) {
    // top barrier: all waves done reading Xl/Xtl of previous tile
    asm volatile("s_waitcnt lgkmcnt(0)" ::: "memory");
    __builtin_amdgcn_s_barrier();
    {
      const int l = lp;
      size_t rowbase = ((size_t)(l0 + t * 64 + l) * BB + b) * DD + h * HDD + c8 * 8;
      bf16x8 v0, v1;
      v0[0] = f2bf(cur0.x); v0[1] = f2bf(cur0.y); v0[2] = f2bf(cur0.z); v0[3] = f2bf(cur0.w);
      v0[4] = f2bf(cur1.x); v0[5] = f2bf(cur1.y); v0[6] = f2bf(cur1.z); v0[7] = f2bf(cur1.w);
      v1[0] = f2bf(cur2.x); v1[1] = f2bf(cur2.y); v1[2] = f2bf(cur2.z); v1[3] = f2bf(cur2.w);
      v1[4] = f2bf(cur3.x); v1[5] = f2bf(cur3.y); v1[6] = f2bf(cur3.z); v1[7] = f2bf(cur3.w);
      // global bf16 copy for q-proj (never read in this kernel -> no drain)
      *(bf16x8*)(qbf_out + rowbase) = v0;
      *(bf16x8*)(qbf_out + rowbase + BB * DD) = v1;
      // LDS tiles
      *(bf16x8*)(Xl + l * 128 + ((c8 ^ (l & 7)) << 4)) = v0;
      *(bf16x8*)(Xl + (l + 1) * 128 + ((c8 ^ ((l + 1) & 7)) << 4)) = v1;
#pragma unroll
      for (int i = 0; i < 8; ++i) {
        int dd = c8 * 8 + i;
        unsigned int packed = (unsigned int)(unsigned short)v0[i] |
                              ((unsigned int)(unsigned short)v1[i] << 16);
        *(unsigned int*)(Xtl + dd * 128 +
            ((((l >> 3) ^ (dd & 7) ^ (dd >> 3)) & 7) << 4) + ((l & 7) << 1)) = packed;
      }
    }
    // prefetch next tile (stays in flight across the barrier below)
    float4 nxt0, nxt1, nxt2, nxt3;
    if (t < 3) {
      const float* xp = q32 +
          ((size_t)(l0 + (t + 1) * 64 + lp) * BB + b) * DD + h * HDD + c8 * 8;
      nxt0 = *(const float4*)xp;       nxt1 = *(const float4*)(xp + 4);
      nxt2 = *(const float4*)(xp + BB * DD); nxt3 = *(const float4*)(xp + BB * DD + 4);
    }
    // staging visible (LDS only); raw barrier keeps prefetch loads flying
    asm volatile("s_waitcnt lgkmcnt(0)" ::: "memory");
    __builtin_amdgcn_s_barrier();
    __builtin_amdgcn_sched_barrier(0);

#pragma unroll
    for (int lt = 0; lt < 4; ++lt) {
      int rl = lt * 16 + fr;
      bf16x8 xa0 = *(const bf16x8*)(Xl + rl * 128 + (((0 + fg) ^ (rl & 7)) << 4));
      bf16x8 xa1 = *(const bf16x8*)(Xl + rl * 128 + (((4 + fg) ^ (rl & 7)) << 4));
#pragma unroll
      for (int pt = 0; pt < 4; ++pt) {
        f32x4 s = (f32x4){0.f, 0.f, 0.f, 0.f};
        s = MFMA16(xa0, ef[pt][0], s);
        s = MFMA16(xa1, ef[pt][1], s);
        short4v pk;
#pragma unroll
        for (int r = 0; r < 4; ++r)
          pk[r] = (short)f2bf(fmaxf(s[r] * kScaling, 0.f));
        int p = wv * 64 + pt * 16 + fr;
        int lbase = lt * 16 + fg * 4;
        int slot = lbase >> 3;
        *(short4v*)(Pl + p * 128 + ((slot ^ (p & 7)) << 4) + ((lbase & 7) << 1)) = pk;
      }
    }
    asm volatile("s_waitcnt lgkmcnt(0)" ::: "memory");
    __builtin_amdgcn_sched_barrier(0);
#pragma unroll
    for (int kc = 0; kc < 2; ++kc) {
      bf16x8 pa[4], xb[4];
#pragma unroll
      for (int pt = 0; pt < 4; ++pt) {
        int p = wv * 64 + pt * 16 + fr;
        pa[pt] = *(const bf16x8*)(Pl + p * 128 + (((kc * 4 + fg) ^ (p & 7)) << 4));
      }
#pragma unroll
      for (int dt = 0; dt < 4; ++dt) {
        int dd = dt * 16 + fr;
        xb[dt] = *(const bf16x8*)(Xtl + dd * 128 +
                  ((((kc * 4 + fg) ^ (dd & 7) ^ (dd >> 3)) & 7) << 4));
      }
#pragma unroll
      for (int pt = 0; pt < 4; ++pt)
#pragma unroll
        for (int dt = 0; dt < 4; ++dt)
          acc[pt][dt] = MFMA16(pa[pt], xb[dt], acc[pt][dt]);
    }
    if (t < 3) { cur0 = nxt0; cur1 = nxt1; cur2 = nxt2; cur3 = nxt3; }
  }
  unsigned short* op = parts + (size_t)(lc * 64 + bh) * PP * HDD;
#pragma unroll
  for (int pt = 0; pt < 4; ++pt)
#pragma unroll
    for (int dt = 0; dt < 4; ++dt)
#pragma unroll
      for (int r = 0; r < 4; ++r) {
        int p = wv * 64 + pt * 16 + fg * 4 + r;
        int dd = dt * 16 + fr;
        op[(size_t)p * HDD + dd] = f2bf(acc[pt][dt][r]);
      }
}

// Sum LC bf16 partials -> kv_raw bf16 as (P,B,D); vectorized x8.
__global__ __launch_bounds__(256) void k_reduce(const unsigned short* __restrict__ parts,
                                                unsigned short* __restrict__ kv_raw_bf) {
  int u = blockIdx.x * 256 + threadIdx.x;     // 131072 units of 8 elems
  size_t off = (size_t)u * 8;
  float s[8] = {0.f, 0.f, 0.f, 0.f, 0.f, 0.f, 0.f, 0.f};
#pragma unroll
  for (int lcc = 0; lcc < LC; ++lcc) {
    bf16x8 v = *(const bf16x8*)(parts + (size_t)lcc * (64 * PP * HDD) + off);
#pragma unroll
    for (int j = 0; j < 8; ++j) s[j] += bf2f((unsigned short)v[j]);
  }
  int i = (int)off;
  int d = i & 63, p = (i >> 6) & 255, bh = i >> 14;
  int b = bh >> 4, h = bh & 15;
  bf16x8 o;
#pragma unroll
  for (int j = 0; j < 8; ++j) o[j] = (short)f2bf(s[j]);
  *(bf16x8*)(kv_raw_bf + (size_t)(p * BB + b) * DD + h * HDD + d) = o;
}

// ---------------------------------------------------------------------------
// 128x128 GEMM body (small P=1024-row GEMMs).
// ---------------------------------------------------------------------------
template <int MODE, typename OUTT>
__device__ __forceinline__ void gemm_body(
    const unsigned short* __restrict__ A, const unsigned short* __restrict__ W,
    const float* __restrict__ bias, const float* __restrict__ ew,
    OUTT* __restrict__ C, int m0, int n0, char* Al, char* Bl) {
  const int tid = threadIdx.x;
  const int wv = tid >> 6, lane = tid & 63;
  const int fr = lane & 15, fg = lane >> 4;
  const int wr = wv >> 1, wc = wv & 1;

  f32x4 acc[4][4];
#pragma unroll
  for (int i = 0; i < 4; ++i)
#pragma unroll
    for (int j = 0; j < 4; ++j) acc[i][j] = (f32x4){0.f, 0.f, 0.f, 0.f};

  for (int k0 = 0; k0 < DD; k0 += 64) {
    __syncthreads();
#pragma unroll
    for (int j = 0; j < 4; ++j) {
      int u = tid + j * 256;
      int row = u >> 3, slot = u & 7;
      size_t gcol = (size_t)(k0 + 8 * (slot ^ (row & 7)));
      gll16(A + (size_t)(m0 + row) * DD + gcol, Al + u * 16);
      gll16(W + (size_t)(n0 + row) * DD + gcol, Bl + u * 16);
    }
    __syncthreads();
#pragma unroll
    for (int kc = 0; kc < 2; ++kc) {
      bf16x8 af[4], bfr[4];
#pragma unroll
      for (int mt = 0; mt < 4; ++mt) {
        int r = wr * 64 + mt * 16 + fr;
        af[mt] = *(const bf16x8*)(Al + r * 128 + (((kc * 4 + fg) ^ (r & 7)) << 4));
      }
#pragma unroll
      for (int nt = 0; nt < 4; ++nt) {
        int r = wc * 64 + nt * 16 + fr;
        bfr[nt] = *(const bf16x8*)(Bl + r * 128 + (((kc * 4 + fg) ^ (r & 7)) << 4));
      }
#pragma unroll
      for (int mt = 0; mt < 4; ++mt)
#pragma unroll
        for (int nt = 0; nt < 4; ++nt)
          acc[mt][nt] = MFMA16(af[mt], bfr[nt], acc[mt][nt]);
    }
  }

  float bs[4];
#pragma unroll
  for (int nt = 0; nt < 4; ++nt) bs[nt] = bias[n0 + wc * 64 + nt * 16 + fr];
#pragma unroll
  for (int mt = 0; mt < 4; ++mt)
#pragma unroll
    for (int nt = 0; nt < 4; ++nt) {
      int n = n0 + wc * 64 + nt * 16 + fr;
#pragma unroll
      for (int r = 0; r < 4; ++r) {
        int m = m0 + wr * 64 + mt * 16 + fg * 4 + r;
        float v = acc[mt][nt][r] + bs[nt];
        if (MODE == 1) v *= kScaling;
        if (MODE == 2) {
          int p = m >> 2, hh = n >> 6, d2 = n & 63;
          v += ew[(size_t)((hh << 8) + p) * HDD + d2];
        }
        if constexpr (sizeof(OUTT) == 2)
          C[(size_t)m * DD + n] = (OUTT)f2bf(v);
        else
          C[(size_t)m * DD + n] = v;
      }
    }
}

template <int MODE, typename OUTT>
__global__ __launch_bounds__(256) void k_gemm_mfma(
    const unsigned short* __restrict__ A, const unsigned short* __restrict__ W,
    const float* __restrict__ bias, const float* __restrict__ ew,
    OUTT* __restrict__ C) {
  __shared__ __align__(16) char Al[16384];
  __shared__ __align__(16) char Bl[16384];
  gemm_body<MODE, OUTT>(A, W, bias, ew, C, blockIdx.x * 128, blockIdx.y * 128, Al, Bl);
}

// K and V projections in one launch (blockIdx.z selects).
__global__ __launch_bounds__(256) void k_gemm_kv(
    const unsigned short* __restrict__ A,
    const unsigned short* __restrict__ Wk, const unsigned short* __restrict__ Wv,
    const float* __restrict__ kb, const float* __restrict__ vb,
    unsigned short* __restrict__ Ck, unsigned short* __restrict__ Cv) {
  __shared__ __align__(16) char Al[16384];
  __shared__ __align__(16) char Bl[16384];
  if (blockIdx.z == 0)
    gemm_body<0, unsigned short>(A, Wk, kb, nullptr, Ck,
                                 blockIdx.x * 128, blockIdx.y * 128, Al, Bl);
  else
    gemm_body<0, unsigned short>(A, Wv, vb, nullptr, Cv,
                                 blockIdx.x * 128, blockIdx.y * 128, Al, Bl);
}

// ---------------------------------------------------------------------------
// 256x256 GEMM, minimal-barrier schedule (unchanged from round 10).
// ---------------------------------------------------------------------------
template <int MODE, typename OUTT>
__global__ __launch_bounds__(512, 2) void k_gemm256(
    const unsigned short* __restrict__ A, const unsigned short* __restrict__ W,
    const float* __restrict__ bias, OUTT* __restrict__ C) {
  __shared__ __align__(16) char lds[131072];
  const int tid = threadIdx.x;
  const int wv = tid >> 6, lane = tid & 63;
  const int fr = lane & 15, fg = lane >> 4;
  const int wm = wv >> 2, wn = wv & 3;
  const int m0 = blockIdx.x * 256, n0 = blockIdx.y * 256;
  const int srow = tid >> 2, sslot = tid & 3;

  auto stageHalf = [&](const unsigned short* __restrict__ G, int g0, int colbase,
                       int dstBase) {
#pragma unroll
    for (int j = 0; j < 2; ++j) {
      int row = srow + j * 128;
      int gs = sslot ^ ((row >> 1) & 3);
      gll16(G + (size_t)(g0 + row) * DD + colbase + gs * 8,
            lds + dstBase + (tid + j * 512) * 16);
    }
  };
  auto rdA = [&](int mf, int kc, int cb) -> bf16x8 {
    int r = wm * 128 + mf * 16 + fr;
    return *(const bf16x8*)(lds + cb + kc * 16384 + r * 64 +
                            ((fg ^ ((r >> 1) & 3)) << 4));
  };
  auto rdB = [&](int nf, int kc, int cb) -> bf16x8 {
    int r = wn * 64 + nf * 16 + fr;
    return *(const bf16x8*)(lds + cb + 32768 + kc * 16384 + r * 64 +
                            ((fg ^ ((r >> 1) & 3)) << 4));
  };

  f32x4 acc[8][4];
#pragma unroll
  for (int i = 0; i < 8; ++i)
#pragma unroll
    for (int j = 0; j < 4; ++j) acc[i][j] = (f32x4){0.f, 0.f, 0.f, 0.f};
  bf16x8 a[8], b[4];

  stageHalf(A, m0, 0, 0);
  stageHalf(W, n0, 0, 32768);
  stageHalf(A, m0, 32, 16384);
  stageHalf(W, n0, 32, 32768 + 16384);
  stageHalf(A, m0, 64, 65536);
  stageHalf(W, n0, 64, 65536 + 32768);
  asm volatile("s_waitcnt vmcnt(4)" ::: "memory");   // tile0 arrived
  __builtin_amdgcn_s_barrier();

  const int NT = DD / 64;   // 16
  for (int t = 0; t < NT; ++t) {
    const int cb = (t & 1) << 16;
    const int nb = cb ^ 65536;
    const int k1 = (t + 1) * 64, k2 = (t + 2) * 64;

    // ---- half 1: kc0 (all mf), stage t+1.kc1 into nb
#pragma unroll
    for (int i = 0; i < 8; ++i) a[i] = rdA(i, 0, cb);
#pragma unroll
    for (int i = 0; i < 4; ++i) b[i] = rdB(i, 0, cb);
    if (t + 1 < NT) {
      stageHalf(A, m0, k1 + 32, nb + 16384);
      stageHalf(W, n0, k1 + 32, nb + 32768 + 16384);
    }
    asm volatile("s_waitcnt lgkmcnt(0)" ::: "memory");
    __builtin_amdgcn_sched_barrier(0);
    __builtin_amdgcn_s_setprio(1);
#pragma unroll
    for (int mf = 0; mf < 8; ++mf)
#pragma unroll
      for (int nf = 0; nf < 4; ++nf)
        acc[mf][nf] = MFMA16(a[mf], b[nf], acc[mf][nf]);
    __builtin_amdgcn_s_setprio(0);
    __builtin_amdgcn_s_barrier();   // mid: kc0 reads done across waves

    // ---- half 2: kc1 (all mf), stage t+2.kc0 into cb
#pragma unroll
    for (int i = 0; i < 8; ++i) a[i] = rdA(i, 1, cb);
#pragma unroll
    for (int i = 0; i < 4; ++i) b[i] = rdB(i, 1, cb);
    if (t + 2 < NT) {
      stageHalf(A, m0, k2, cb);
      stageHalf(W, n0, k2, cb + 32768);
    }
    asm volatile("s_waitcnt lgkmcnt(0)" ::: "memory");
    __builtin_amdgcn_sched_barrier(0);
    __builtin_amdgcn_s_setprio(1);
#pragma unroll
    for (int mf = 0; mf < 8; ++mf)
#pragma unroll
      for (int nf = 0; nf < 4; ++nf)
        acc[mf][nf] = MFMA16(a[mf], b[nf], acc[mf][nf]);
    __builtin_amdgcn_s_setprio(0);
    if (t + 2 < NT) {
      asm volatile("s_waitcnt vmcnt(4)" ::: "memory");   // t+1 fully arrived
    } else if (t + 1 < NT) {
      asm volatile("s_waitcnt vmcnt(0)" ::: "memory");   // drain for last tile
    }
    __builtin_amdgcn_s_barrier();   // end of tile
  }

  float bs[4];
#pragma unroll
  for (int nf = 0; nf < 4; ++nf) bs[nf] = bias[n0 + wn * 64 + nf * 16 + fr];
#pragma unroll
  for (int mf = 0; mf < 8; ++mf)
#pragma unroll
    for (int nf = 0; nf < 4; ++nf) {
      int n = n0 + wn * 64 + nf * 16 + fr;
#pragma unroll
      for (int r = 0; r < 4; ++r) {
        int m = m0 + wm * 128 + mf * 16 + fg * 4 + r;
        float v = acc[mf][nf][r] + bs[nf];
        if (MODE == 1) v *= kScaling;
        if constexpr (sizeof(OUTT) == 2)
          C[(size_t)m * DD + n] = (OUTT)f2bf(v);
        else
          C[(size_t)m * DD + n] = v;
      }
    }
}

// LayerNorm over D=1024; fp32 in -> bf16 out. One block per row.
__global__ __launch_bounds__(256) void k_ln(const float* __restrict__ x,
                                            const float* __restrict__ g,
                                            const float* __restrict__ bb,
                                            unsigned short* __restrict__ y) {
  const int r = blockIdx.x;
  const int tid = threadIdx.x;
  const float* xr = x + (size_t)r * DD;
  float4 v = *(const float4*)(xr + tid * 4);
  float s1 = v.x + v.y + v.z + v.w;
  float s2 = v.x * v.x + v.y * v.y + v.z * v.z + v.w * v.w;
#pragma unroll
  for (int off = 32; off > 0; off >>= 1) {
    s1 += __shfl_down(s1, off);
    s2 += __shfl_down(s2, off);
  }
  __shared__ float w1[4], w2[4];
  if ((tid & 63) == 0) { w1[tid >> 6] = s1; w2[tid >> 6] = s2; }
  __syncthreads();
  float S1 = w1[0] + w1[1] + w1[2] + w1[3];
  float S2 = w2[0] + w2[1] + w2[2] + w2[3];
  float mean = S1 * (1.f / DD);
  float var = S2 * (1.f / DD) - mean * mean;
  float rstd = rsqrtf(var + kEps);
  float4 gv = *(const float4*)(g + tid * 4);
  float4 bv = *(const float4*)(bb + tid * 4);
  short4v o;
  o[0] = (short)f2bf((v.x - mean) * rstd * gv.x + bv.x);
  o[1] = (short)f2bf((v.y - mean) * rstd * gv.y + bv.y);
  o[2] = (short)f2bf((v.z - mean) * rstd * gv.z + bv.z);
  o[3] = (short)f2bf((v.w - mean) * rstd * gv.w + bv.w);
  *(short4v*)(y + (size_t)r * DD + tid * 4) = o;
}

// ---------------------------------------------------------------------------
// Attention: QBLK=128. T14: ph1's V-tile prefetched into regs during ph0;
// raw barriers + counted vmcnt(2) keep the prefetch in flight (K gll16
// issued FIRST so vmcnt(2) waits K and leaves the 2 V loads flying).
// ---------------------------------------------------------------------------
__global__ __launch_bounds__(512, 2) void k_attn_mfma(
    const unsigned short* __restrict__ qbf, const unsigned short* __restrict__ kbf,
    const unsigned short* __restrict__ vbf, unsigned short* __restrict__ attn) {
  const int bh = blockIdx.y;
  const int b = bh >> 4, h = bh & 15;
  const int tid = threadIdx.x, wv = tid >> 6, lane = tid & 63;
  const int fr = lane & 15, fg = lane >> 4;
  const int bl0 = blockIdx.x * 128;

  __shared__ __align__(16) char Kl[16384];    // [128p][64d] swz rows of 128B
  __shared__ __align__(16) char Vt[16384];    // 2 chunks of [64 dd][64 p]
  __shared__ __align__(16) char Pl[32768];    // 8 waves x [16 l][128 p]

  const size_t qrow = ((size_t)(bl0 + wv * 16 + fr) * BB + b) * DD + h * HDD;
  bf16x8 qf0 = *(const bf16x8*)(qbf + qrow + fg * 8);
  bf16x8 qf1 = *(const bf16x8*)(qbf + qrow + 32 + fg * 8);

  f32x4 o[4];
#pragma unroll
  for (int dt = 0; dt < 4; ++dt) o[dt] = (f32x4){0.f, 0.f, 0.f, 0.f};
  float psum = 0.f;
  char* Pw = Pl + wv * 4096;

  const int p2 = tid >> 3, c8v = tid & 7;
  const size_t vbase = ((size_t)((2 * p2) * BB + b)) * DD + h * HDD + c8v * 8;
  // prologue: ph0 V loads -> regs
  bf16x8 va = *(const bf16x8*)(vbf + vbase);
  bf16x8 vb_ = *(const bf16x8*)(vbf + vbase + BB * DD);

#pragma unroll
  for (int ph = 0; ph < 2; ++ph) {
    if (ph == 1) {
      // PV(ph0) ds_reads consumed; raw barrier (V-prefetch stays in flight)
      asm volatile("s_waitcnt lgkmcnt(0)" ::: "memory");
      __builtin_amdgcn_s_barrier();
    }
    // K gll16 first (so counted vmcnt below targets exactly these)
#pragma unroll
    for (int j = 0; j < 2; ++j) {
      int u = tid + j * 512;
      int p = u >> 3, slot = u & 7;
      gll16(kbf + ((size_t)((ph * 128 + p) * BB + b)) * DD + h * HDD +
                8 * (slot ^ (p & 7)),
            Kl + u * 16);
    }
    // V LDS writes from regs (reg-dep wait covers the V loads)
    {
      int pl = (2 * p2) & 63, pc = p2 >> 5;
      char* base = Vt + pc * 8192;
#pragma unroll
      for (int i = 0; i < 8; ++i) {
        int dd = c8v * 8 + i;
        unsigned int packed = (unsigned int)(unsigned short)va[i] |
                              ((unsigned int)(unsigned short)vb_[i] << 16);
        *(unsigned int*)(base + dd * 128 +
            ((((pl >> 3) ^ (dd & 7) ^ (dd >> 3)) & 7) << 4) + ((pl & 7) << 1)) = packed;
      }
    }
    bf16x8 van, vbn;
    if (ph == 0) {   // prefetch ph1 V (rows +128)
      van = *(const bf16x8*)(vbf + vbase + (size_t)128 * BB * DD);
      vbn = *(const bf16x8*)(vbf + vbase + (size_t)129 * BB * DD);
    }
    asm volatile("s_waitcnt lgkmcnt(0)" ::: "memory");
    if (ph == 0) {
      asm volatile("s_waitcnt vmcnt(2)" ::: "memory");   // K done, V-prefetch flying
    } else {
      asm volatile("s_waitcnt vmcnt(0)" ::: "memory");   // K done (nothing else)
    }
    __builtin_amdgcn_s_barrier();
    __builtin_amdgcn_sched_barrier(0);

    f32x4 s[8];
    __builtin_amdgcn_s_setprio(1);
#pragma unroll
    for (int pt = 0; pt < 8; ++pt) {
      int pr = pt * 16 + fr;
      bf16x8 a0 = *(const bf16x8*)(Kl + pr * 128 + ((fg ^ (pr & 7)) << 4));
      bf16x8 a1 = *(const bf16x8*)(Kl + pr * 128 + (((4 + fg) ^ (pr & 7)) << 4));
      f32x4 acc = (f32x4){0.f, 0.f, 0.f, 0.f};
      acc = MFMA16(a0, qf0, acc);
      acc = MFMA16(a1, qf1, acc);
      s[pt] = acc;
    }
    __builtin_amdgcn_s_setprio(0);

#pragma unroll
    for (int pt = 0; pt < 8; ++pt) {
      float e0 = __expf(s[pt][0]), e1 = __expf(s[pt][1]);
      float e2 = __expf(s[pt][2]), e3 = __expf(s[pt][3]);
      psum += (e0 + e1) + (e2 + e3);
      short4v pk;
      pk[0] = (short)f2bf(e0); pk[1] = (short)f2bf(e1);
      pk[2] = (short)f2bf(e2); pk[3] = (short)f2bf(e3);
      int pbyte = (pt * 16 + fg * 4) * 2;
      int slot = pbyte >> 4, rem = pbyte & 15;
      *(short4v*)(Pw + fr * 256 + ((slot ^ (fr & 7)) << 4) + rem) = pk;
    }
    asm volatile("s_waitcnt lgkmcnt(0)" ::: "memory");
    __builtin_amdgcn_sched_barrier(0);

    __builtin_amdgcn_s_setprio(1);
#pragma unroll
    for (int kc = 0; kc < 4; ++kc) {
      int slot = kc * 4 + fg;
      bf16x8 pa = *(const bf16x8*)(Pw + fr * 256 + ((slot ^ (fr & 7)) << 4));
      int sl2 = (kc & 1) * 4 + fg;
#pragma unroll
      for (int dt = 0; dt < 4; ++dt) {
        int dd = dt * 16 + fr;
        bf16x8 vbr = *(const bf16x8*)(Vt + (kc >> 1) * 8192 + dd * 128 +
                     (((sl2 ^ (dd & 7) ^ (dd >> 3)) & 7) << 4));
        o[dt] = MFMA16(pa, vbr, o[dt]);
      }
    }
    __builtin_amdgcn_s_setprio(0);

    if (ph == 0) { va = van; vb_ = vbn; }
  }

  psum += __shfl_xor(psum, 16);
  psum += __shfl_xor(psum, 32);

#pragma unroll
  for (int r = 0; r < 4; ++r) {
    int lloc = fg * 4 + r;
    float inv = 1.f / __shfl(psum, lloc);
    unsigned short* op = attn +
        ((size_t)(bl0 + wv * 16 + lloc) * BB + b) * DD + h * HDD;
#pragma unroll
    for (int dt = 0; dt < 4; ++dt)
      op[dt * 16 + fr] = f2bf(o[dt][r] * inv);
  }
}

extern "C" void kernel_launch(void* const* d_in, const int* in_sizes, int n_in,
                              void* d_out, int out_size, void* d_ws, size_t ws_size,
                              hipStream_t stream) {
  const float* query   = (const float*)d_in[0];
  const float* q_w     = (const float*)d_in[1];
  const float* q_b     = (const float*)d_in[2];
  const float* k_w     = (const float*)d_in[3];
  const float* k_b     = (const float*)d_in[4];
  const float* v_w     = (const float*)d_in[5];
  const float* v_b     = (const float*)d_in[6];
  const float* e_weight= (const float*)d_in[7];
  const float* e_out_w = (const float*)d_in[8];
  const float* e_out_b = (const float*)d_in[9];
  const float* ln_g    = (const float*)d_in[10];
  const float* ln_b    = (const float*)d_in[11];
  const float* out_w   = (const float*)d_in[12];
  const float* out_b   = (const float*)d_in[13];
  float* out = (float*)d_out;

  char* w = (char*)d_ws;
  unsigned short* parts   = (unsigned short*)w;                 // 32 MB, dead after reduce
  unsigned short* q_bf    = (unsigned short*)w;                 // 32 MB (alias, after reduce)
  unsigned short* attn_bf = (unsigned short*)(w + (32u << 20)); // 32 MB
  unsigned short* query_bf= (unsigned short*)(w + (64u << 20)); // 32 MB
  unsigned short* kv_raw  = (unsigned short*)(w + (96u << 20)); // 2 MB
  float* kv_eo            = (float*)(w + (98u << 20));          // 4 MB
  unsigned short* kv_ln   = (unsigned short*)(w + (102u << 20));// 2 MB
  unsigned short* k_buf   = (unsigned short*)(w + (104u << 20));// 2 MB
  unsigned short* v_buf   = (unsigned short*)(w + (106u << 20));// 2 MB
  unsigned short* wq  = (unsigned short*)(w + (108u << 20));
  unsigned short* wk  = (unsigned short*)(w + (110u << 20));
  unsigned short* wv_ = (unsigned short*)(w + (112u << 20));
  unsigned short* weo = (unsigned short*)(w + (114u << 20));
  unsigned short* wo  = (unsigned short*)(w + (116u << 20));
  unsigned short* ewb = (unsigned short*)(w + (118u << 20));    // 0.5 MB

  k_cvt_w<<<2688, 256, 0, stream>>>(q_w, k_w, v_w, e_out_w, out_w, e_weight,
                                    wq, wk, wv_, weo, wo, ewb);

  k_compress_mfma<<<dim3(64, LC), 256, 0, stream>>>(query, ewb, query_bf, parts);
  k_reduce<<<512, 256, 0, stream>>>(parts, kv_raw);
  k_gemm_mfma<2, float><<<dim3(8, 8), 256, 0, stream>>>(kv_raw, weo, e_out_b, e_weight, kv_eo);
  k_ln<<<PP * BB, 256, 0, stream>>>(kv_eo, ln_g, ln_b, kv_ln);
  k_gemm256<1, unsigned short><<<dim3(64, 4), 512, 0, stream>>>(query_bf, wq, q_b, q_bf);
  k_gemm_kv<<<dim3(8, 8, 2), 256, 0, stream>>>(kv_ln, wk, wv_, k_b, v_b, k_buf, v_buf);
  k_attn_mfma<<<dim3(32, 64), 512, 0, stream>>>(q_bf, k_buf, v_buf, attn_bf);
  k_gemm256<0, float><<<dim3(64, 4), 512, 0, stream>>>(attn_bf, wo, out_b, out);
}

// Round 13
// 212.259 us; speedup vs baseline: 1.0140x; 1.0140x over previous
//
#include <hip/hip_runtime.h>
#include <hip/hip_bf16.h>
#include <cstdint>
#include <cstddef>

#define LL 4096
#define BB 4
#define DD 1024
#define HH 16
#define PP 256
#define HDD 64
#define LC 16
#define LCHUNK 256

constexpr float kScaling = 0.125f;   // HD^-0.5
constexpr float kEps = 1e-5f;

typedef __attribute__((ext_vector_type(8))) short bf16x8;   // 8 bf16 = 4 VGPR
typedef __attribute__((ext_vector_type(4))) short short4v;
typedef __attribute__((ext_vector_type(4))) float f32x4;

#define MFMA16(a, b, c) __builtin_amdgcn_mfma_f32_16x16x32_bf16((a), (b), (c), 0, 0, 0)

__device__ __forceinline__ unsigned short f2bf(float f) {
  unsigned int u = __builtin_bit_cast(unsigned int, f);
  u += 0x7FFFu + ((u >> 16) & 1u);           // round-to-nearest-even
  return (unsigned short)(u >> 16);
}
__device__ __forceinline__ float bf2f(unsigned short u) {
  return __builtin_bit_cast(float, ((unsigned int)u) << 16);
}

__device__ __forceinline__ void gll16(const void* g, void* l) {
  __builtin_amdgcn_global_load_lds(
      (const __attribute__((address_space(1))) unsigned int*)g,
      (__attribute__((address_space(3))) unsigned int*)l, 16, 0, 0);
}

// ---------------------------------------------------------------------------
// Weights-only fp32 -> bf16 convert.
// ---------------------------------------------------------------------------
__global__ __launch_bounds__(256) void k_cvt_w(
    const float* __restrict__ w0, const float* __restrict__ w1,
    const float* __restrict__ w2, const float* __restrict__ w3,
    const float* __restrict__ w4, const float* __restrict__ w5,
    unsigned short* __restrict__ d0, unsigned short* __restrict__ d1,
    unsigned short* __restrict__ d2, unsigned short* __restrict__ d3,
    unsigned short* __restrict__ d4, unsigned short* __restrict__ d5) {
  int i = blockIdx.x * 256 + threadIdx.x;
  int w = i >> 17, off = i & 131071;
  const float* src; unsigned short* dst;
  if (w == 0) { src = w0; dst = d0; }
  else if (w == 1) { src = w1; dst = d1; }
  else if (w == 2) { src = w2; dst = d2; }
  else if (w == 3) { src = w3; dst = d3; }
  else if (w == 4) { src = w4; dst = d4; }
  else { if (off >= 32768) return; src = w5; dst = d5; }
  const float4* s = (const float4*)(src + (size_t)off * 8);
  float4 a = s[0], b = s[1];
  bf16x8 o;
  o[0] = f2bf(a.x); o[1] = f2bf(a.y); o[2] = f2bf(a.z); o[3] = f2bf(a.w);
  o[4] = f2bf(b.x); o[5] = f2bf(b.y); o[6] = f2bf(b.z); o[7] = f2bf(b.w);
  *(bf16x8*)(dst + (size_t)off * 8) = o;
}

// ---------------------------------------------------------------------------
// Compress (MFMA) + inline query cvt (round-11 version: no reg prefetch).
// Xtl transpose staged as packed p-pair ds_write_b32.
// ---------------------------------------------------------------------------
__global__ __launch_bounds__(256) void k_compress_mfma(
    const float* __restrict__ q32, const unsigned short* __restrict__ ewbf,
    unsigned short* __restrict__ qbf_out, unsigned short* __restrict__ parts) {
  const int bh = blockIdx.x, lc = blockIdx.y;
  const int b = bh >> 4, h = bh & 15;
  const int tid = threadIdx.x, wv = tid >> 6, lane = tid & 63;
  const int fr = lane & 15, fg = lane >> 4;

  __shared__ __align__(16) char Xl[8192];    // [l][d] rows of 128B
  __shared__ __align__(16) char Xtl[8192];   // [d][l]
  __shared__ __align__(16) char Pl[32768];   // [p][l] rows of 128B

  bf16x8 ef[4][2];
#pragma unroll
  for (int pt = 0; pt < 4; ++pt)
#pragma unroll
    for (int kc = 0; kc < 2; ++kc)
      ef[pt][kc] = *(const bf16x8*)(ewbf +
          (size_t)((h * PP + wv * 64 + pt * 16 + fr) * HDD) + kc * 32 + fg * 8);

  f32x4 acc[4][4];
#pragma unroll
  for (int i = 0; i < 4; ++i)
#pragma unroll
    for (int j = 0; j < 4; ++j) acc[i][j] = (f32x4){0.f, 0.f, 0.f, 0.f};

  const int l0 = lc * LCHUNK;
  for (int t = 0; t < 4; ++t) {
    __syncthreads();
    {
      int l2 = tid >> 3, c8 = tid & 7;
      int l = 2 * l2;
      size_t rowbase = ((size_t)(l0 + t * 64 + l) * BB + b) * DD + h * HDD + c8 * 8;
      const float* xp = q32 + rowbase;
      float4 a0 = *(const float4*)xp;
      float4 a1 = *(const float4*)(xp + 4);
      float4 b0 = *(const float4*)(xp + BB * DD);
      float4 b1 = *(const float4*)(xp + BB * DD + 4);
      bf16x8 v0, v1;
      v0[0] = f2bf(a0.x); v0[1] = f2bf(a0.y); v0[2] = f2bf(a0.z); v0[3] = f2bf(a0.w);
      v0[4] = f2bf(a1.x); v0[5] = f2bf(a1.y); v0[6] = f2bf(a1.z); v0[7] = f2bf(a1.w);
      v1[0] = f2bf(b0.x); v1[1] = f2bf(b0.y); v1[2] = f2bf(b0.z); v1[3] = f2bf(b0.w);
      v1[4] = f2bf(b1.x); v1[5] = f2bf(b1.y); v1[6] = f2bf(b1.z); v1[7] = f2bf(b1.w);
      // global bf16 copy for q-proj (each (l,b,h,d) written exactly once)
      *(bf16x8*)(qbf_out + rowbase) = v0;
      *(bf16x8*)(qbf_out + rowbase + BB * DD) = v1;
      // LDS tiles
      *(bf16x8*)(Xl + l * 128 + ((c8 ^ (l & 7)) << 4)) = v0;
      *(bf16x8*)(Xl + (l + 1) * 128 + ((c8 ^ ((l + 1) & 7)) << 4)) = v1;
#pragma unroll
      for (int i = 0; i < 8; ++i) {
        int dd = c8 * 8 + i;
        unsigned int packed = (unsigned int)(unsigned short)v0[i] |
                              ((unsigned int)(unsigned short)v1[i] << 16);
        *(unsigned int*)(Xtl + dd * 128 +
            ((((l >> 3) ^ (dd & 7) ^ (dd >> 3)) & 7) << 4) + ((l & 7) << 1)) = packed;
      }
    }
    __syncthreads();
#pragma unroll
    for (int lt = 0; lt < 4; ++lt) {
      int rl = lt * 16 + fr;
      bf16x8 xa0 = *(const bf16x8*)(Xl + rl * 128 + (((0 + fg) ^ (rl & 7)) << 4));
      bf16x8 xa1 = *(const bf16x8*)(Xl + rl * 128 + (((4 + fg) ^ (rl & 7)) << 4));
#pragma unroll
      for (int pt = 0; pt < 4; ++pt) {
        f32x4 s = (f32x4){0.f, 0.f, 0.f, 0.f};
        s = MFMA16(xa0, ef[pt][0], s);
        s = MFMA16(xa1, ef[pt][1], s);
        short4v pk;
#pragma unroll
        for (int r = 0; r < 4; ++r)
          pk[r] = (short)f2bf(fmaxf(s[r] * kScaling, 0.f));
        int p = wv * 64 + pt * 16 + fr;
        int lbase = lt * 16 + fg * 4;
        int slot = lbase >> 3;
        *(short4v*)(Pl + p * 128 + ((slot ^ (p & 7)) << 4) + ((lbase & 7) << 1)) = pk;
      }
    }
    asm volatile("s_waitcnt lgkmcnt(0)" ::: "memory");
    __builtin_amdgcn_sched_barrier(0);
#pragma unroll
    for (int kc = 0; kc < 2; ++kc) {
      bf16x8 pa[4], xb[4];
#pragma unroll
      for (int pt = 0; pt < 4; ++pt) {
        int p = wv * 64 + pt * 16 + fr;
        pa[pt] = *(const bf16x8*)(Pl + p * 128 + (((kc * 4 + fg) ^ (p & 7)) << 4));
      }
#pragma unroll
      for (int dt = 0; dt < 4; ++dt) {
        int dd = dt * 16 + fr;
        xb[dt] = *(const bf16x8*)(Xtl + dd * 128 +
                  ((((kc * 4 + fg) ^ (dd & 7) ^ (dd >> 3)) & 7) << 4));
      }
#pragma unroll
      for (int pt = 0; pt < 4; ++pt)
#pragma unroll
        for (int dt = 0; dt < 4; ++dt)
          acc[pt][dt] = MFMA16(pa[pt], xb[dt], acc[pt][dt]);
    }
  }
  unsigned short* op = parts + (size_t)(lc * 64 + bh) * PP * HDD;
#pragma unroll
  for (int pt = 0; pt < 4; ++pt)
#pragma unroll
    for (int dt = 0; dt < 4; ++dt)
#pragma unroll
      for (int r = 0; r < 4; ++r) {
        int p = wv * 64 + pt * 16 + fg * 4 + r;
        int dd = dt * 16 + fr;
        op[(size_t)p * HDD + dd] = f2bf(acc[pt][dt][r]);
      }
}

// Sum LC bf16 partials -> kv_raw bf16 as (P,B,D); vectorized x8.
__global__ __launch_bounds__(256) void k_reduce(const unsigned short* __restrict__ parts,
                                                unsigned short* __restrict__ kv_raw_bf) {
  int u = blockIdx.x * 256 + threadIdx.x;     // 131072 units of 8 elems
  size_t off = (size_t)u * 8;
  float s[8] = {0.f, 0.f, 0.f, 0.f, 0.f, 0.f, 0.f, 0.f};
#pragma unroll
  for (int lcc = 0; lcc < LC; ++lcc) {
    bf16x8 v = *(const bf16x8*)(parts + (size_t)lcc * (64 * PP * HDD) + off);
#pragma unroll
    for (int j = 0; j < 8; ++j) s[j] += bf2f((unsigned short)v[j]);
  }
  int i = (int)off;
  int d = i & 63, p = (i >> 6) & 255, bh = i >> 14;
  int b = bh >> 4, h = bh & 15;
  bf16x8 o;
#pragma unroll
  for (int j = 0; j < 8; ++j) o[j] = (short)f2bf(s[j]);
  *(bf16x8*)(kv_raw_bf + (size_t)(p * BB + b) * DD + h * HDD + d) = o;
}

// ---------------------------------------------------------------------------
// 128x128 GEMM body (small P=1024-row GEMMs).
// ---------------------------------------------------------------------------
template <int MODE, typename OUTT>
__device__ __forceinline__ void gemm_body(
    const unsigned short* __restrict__ A, const unsigned short* __restrict__ W,
    const float* __restrict__ bias, const float* __restrict__ ew,
    OUTT* __restrict__ C, int m0, int n0, char* Al, char* Bl) {
  const int tid = threadIdx.x;
  const int wv = tid >> 6, lane = tid & 63;
  const int fr = lane & 15, fg = lane >> 4;
  const int wr = wv >> 1, wc = wv & 1;

  f32x4 acc[4][4];
#pragma unroll
  for (int i = 0; i < 4; ++i)
#pragma unroll
    for (int j = 0; j < 4; ++j) acc[i][j] = (f32x4){0.f, 0.f, 0.f, 0.f};

  for (int k0 = 0; k0 < DD; k0 += 64) {
    __syncthreads();
#pragma unroll
    for (int j = 0; j < 4; ++j) {
      int u = tid + j * 256;
      int row = u >> 3, slot = u & 7;
      size_t gcol = (size_t)(k0 + 8 * (slot ^ (row & 7)));
      gll16(A + (size_t)(m0 + row) * DD + gcol, Al + u * 16);
      gll16(W + (size_t)(n0 + row) * DD + gcol, Bl + u * 16);
    }
    __syncthreads();
#pragma unroll
    for (int kc = 0; kc < 2; ++kc) {
      bf16x8 af[4], bfr[4];
#pragma unroll
      for (int mt = 0; mt < 4; ++mt) {
        int r = wr * 64 + mt * 16 + fr;
        af[mt] = *(const bf16x8*)(Al + r * 128 + (((kc * 4 + fg) ^ (r & 7)) << 4));
      }
#pragma unroll
      for (int nt = 0; nt < 4; ++nt) {
        int r = wc * 64 + nt * 16 + fr;
        bfr[nt] = *(const bf16x8*)(Bl + r * 128 + (((kc * 4 + fg) ^ (r & 7)) << 4));
      }
#pragma unroll
      for (int mt = 0; mt < 4; ++mt)
#pragma unroll
        for (int nt = 0; nt < 4; ++nt)
          acc[mt][nt] = MFMA16(af[mt], bfr[nt], acc[mt][nt]);
    }
  }

  float bs[4];
#pragma unroll
  for (int nt = 0; nt < 4; ++nt) bs[nt] = bias[n0 + wc * 64 + nt * 16 + fr];
#pragma unroll
  for (int mt = 0; mt < 4; ++mt)
#pragma unroll
    for (int nt = 0; nt < 4; ++nt) {
      int n = n0 + wc * 64 + nt * 16 + fr;
#pragma unroll
      for (int r = 0; r < 4; ++r) {
        int m = m0 + wr * 64 + mt * 16 + fg * 4 + r;
        float v = acc[mt][nt][r] + bs[nt];
        if (MODE == 1) v *= kScaling;
        if (MODE == 2) {
          int p = m >> 2, hh = n >> 6, d2 = n & 63;
          v += ew[(size_t)((hh << 8) + p) * HDD + d2];
        }
        if constexpr (sizeof(OUTT) == 2)
          C[(size_t)m * DD + n] = (OUTT)f2bf(v);
        else
          C[(size_t)m * DD + n] = v;
      }
    }
}

template <int MODE, typename OUTT>
__global__ __launch_bounds__(256) void k_gemm_mfma(
    const unsigned short* __restrict__ A, const unsigned short* __restrict__ W,
    const float* __restrict__ bias, const float* __restrict__ ew,
    OUTT* __restrict__ C) {
  __shared__ __align__(16) char Al[16384];
  __shared__ __align__(16) char Bl[16384];
  gemm_body<MODE, OUTT>(A, W, bias, ew, C, blockIdx.x * 128, blockIdx.y * 128, Al, Bl);
}

// K and V projections in one launch (blockIdx.z selects).
__global__ __launch_bounds__(256) void k_gemm_kv(
    const unsigned short* __restrict__ A,
    const unsigned short* __restrict__ Wk, const unsigned short* __restrict__ Wv,
    const float* __restrict__ kb, const float* __restrict__ vb,
    unsigned short* __restrict__ Ck, unsigned short* __restrict__ Cv) {
  __shared__ __align__(16) char Al[16384];
  __shared__ __align__(16) char Bl[16384];
  if (blockIdx.z == 0)
    gemm_body<0, unsigned short>(A, Wk, kb, nullptr, Ck,
                                 blockIdx.x * 128, blockIdx.y * 128, Al, Bl);
  else
    gemm_body<0, unsigned short>(A, Wv, vb, nullptr, Cv,
                                 blockIdx.x * 128, blockIdx.y * 128, Al, Bl);
}

// ---------------------------------------------------------------------------
// 256x256 GEMM, minimal-barrier schedule (unchanged).
// ---------------------------------------------------------------------------
template <int MODE, typename OUTT>
__global__ __launch_bounds__(512, 2) void k_gemm256(
    const unsigned short* __restrict__ A, const unsigned short* __restrict__ W,
    const float* __restrict__ bias, OUTT* __restrict__ C) {
  __shared__ __align__(16) char lds[131072];
  const int tid = threadIdx.x;
  const int wv = tid >> 6, lane = tid & 63;
  const int fr = lane & 15, fg = lane >> 4;
  const int wm = wv >> 2, wn = wv & 3;
  const int m0 = blockIdx.x * 256, n0 = blockIdx.y * 256;
  const int srow = tid >> 2, sslot = tid & 3;

  auto stageHalf = [&](const unsigned short* __restrict__ G, int g0, int colbase,
                       int dstBase) {
#pragma unroll
    for (int j = 0; j < 2; ++j) {
      int row = srow + j * 128;
      int gs = sslot ^ ((row >> 1) & 3);
      gll16(G + (size_t)(g0 + row) * DD + colbase + gs * 8,
            lds + dstBase + (tid + j * 512) * 16);
    }
  };
  auto rdA = [&](int mf, int kc, int cb) -> bf16x8 {
    int r = wm * 128 + mf * 16 + fr;
    return *(const bf16x8*)(lds + cb + kc * 16384 + r * 64 +
                            ((fg ^ ((r >> 1) & 3)) << 4));
  };
  auto rdB = [&](int nf, int kc, int cb) -> bf16x8 {
    int r = wn * 64 + nf * 16 + fr;
    return *(const bf16x8*)(lds + cb + 32768 + kc * 16384 + r * 64 +
                            ((fg ^ ((r >> 1) & 3)) << 4));
  };

  f32x4 acc[8][4];
#pragma unroll
  for (int i = 0; i < 8; ++i)
#pragma unroll
    for (int j = 0; j < 4; ++j) acc[i][j] = (f32x4){0.f, 0.f, 0.f, 0.f};
  bf16x8 a[8], b[4];

  stageHalf(A, m0, 0, 0);
  stageHalf(W, n0, 0, 32768);
  stageHalf(A, m0, 32, 16384);
  stageHalf(W, n0, 32, 32768 + 16384);
  stageHalf(A, m0, 64, 65536);
  stageHalf(W, n0, 64, 65536 + 32768);
  asm volatile("s_waitcnt vmcnt(4)" ::: "memory");   // tile0 arrived
  __builtin_amdgcn_s_barrier();

  const int NT = DD / 64;   // 16
  for (int t = 0; t < NT; ++t) {
    const int cb = (t & 1) << 16;
    const int nb = cb ^ 65536;
    const int k1 = (t + 1) * 64, k2 = (t + 2) * 64;

    // ---- half 1: kc0 (all mf), stage t+1.kc1 into nb
#pragma unroll
    for (int i = 0; i < 8; ++i) a[i] = rdA(i, 0, cb);
#pragma unroll
    for (int i = 0; i < 4; ++i) b[i] = rdB(i, 0, cb);
    if (t + 1 < NT) {
      stageHalf(A, m0, k1 + 32, nb + 16384);
      stageHalf(W, n0, k1 + 32, nb + 32768 + 16384);
    }
    asm volatile("s_waitcnt lgkmcnt(0)" ::: "memory");
    __builtin_amdgcn_sched_barrier(0);
    __builtin_amdgcn_s_setprio(1);
#pragma unroll
    for (int mf = 0; mf < 8; ++mf)
#pragma unroll
      for (int nf = 0; nf < 4; ++nf)
        acc[mf][nf] = MFMA16(a[mf], b[nf], acc[mf][nf]);
    __builtin_amdgcn_s_setprio(0);
    __builtin_amdgcn_s_barrier();   // mid: kc0 reads done across waves

    // ---- half 2: kc1 (all mf), stage t+2.kc0 into cb
#pragma unroll
    for (int i = 0; i < 8; ++i) a[i] = rdA(i, 1, cb);
#pragma unroll
    for (int i = 0; i < 4; ++i) b[i] = rdB(i, 1, cb);
    if (t + 2 < NT) {
      stageHalf(A, m0, k2, cb);
      stageHalf(W, n0, k2, cb + 32768);
    }
    asm volatile("s_waitcnt lgkmcnt(0)" ::: "memory");
    __builtin_amdgcn_sched_barrier(0);
    __builtin_amdgcn_s_setprio(1);
#pragma unroll
    for (int mf = 0; mf < 8; ++mf)
#pragma unroll
      for (int nf = 0; nf < 4; ++nf)
        acc[mf][nf] = MFMA16(a[mf], b[nf], acc[mf][nf]);
    __builtin_amdgcn_s_setprio(0);
    if (t + 2 < NT) {
      asm volatile("s_waitcnt vmcnt(4)" ::: "memory");   // t+1 fully arrived
    } else if (t + 1 < NT) {
      asm volatile("s_waitcnt vmcnt(0)" ::: "memory");   // drain for last tile
    }
    __builtin_amdgcn_s_barrier();   // end of tile
  }

  float bs[4];
#pragma unroll
  for (int nf = 0; nf < 4; ++nf) bs[nf] = bias[n0 + wn * 64 + nf * 16 + fr];
#pragma unroll
  for (int mf = 0; mf < 8; ++mf)
#pragma unroll
    for (int nf = 0; nf < 4; ++nf) {
      int n = n0 + wn * 64 + nf * 16 + fr;
#pragma unroll
      for (int r = 0; r < 4; ++r) {
        int m = m0 + wm * 128 + mf * 16 + fg * 4 + r;
        float v = acc[mf][nf][r] + bs[nf];
        if (MODE == 1) v *= kScaling;
        if constexpr (sizeof(OUTT) == 2)
          C[(size_t)m * DD + n] = (OUTT)f2bf(v);
        else
          C[(size_t)m * DD + n] = v;
      }
    }
}

// LayerNorm over D=1024; fp32 in -> bf16 out. One block per row.
__global__ __launch_bounds__(256) void k_ln(const float* __restrict__ x,
                                            const float* __restrict__ g,
                                            const float* __restrict__ bb,
                                            unsigned short* __restrict__ y) {
  const int r = blockIdx.x;
  const int tid = threadIdx.x;
  const float* xr = x + (size_t)r * DD;
  float4 v = *(const float4*)(xr + tid * 4);
  float s1 = v.x + v.y + v.z + v.w;
  float s2 = v.x * v.x + v.y * v.y + v.z * v.z + v.w * v.w;
#pragma unroll
  for (int off = 32; off > 0; off >>= 1) {
    s1 += __shfl_down(s1, off);
    s2 += __shfl_down(s2, off);
  }
  __shared__ float w1[4], w2[4];
  if ((tid & 63) == 0) { w1[tid >> 6] = s1; w2[tid >> 6] = s2; }
  __syncthreads();
  float S1 = w1[0] + w1[1] + w1[2] + w1[3];
  float S2 = w2[0] + w2[1] + w2[2] + w2[3];
  float mean = S1 * (1.f / DD);
  float var = S2 * (1.f / DD) - mean * mean;
  float rstd = rsqrtf(var + kEps);
  float4 gv = *(const float4*)(g + tid * 4);
  float4 bv = *(const float4*)(bb + tid * 4);
  short4v o;
  o[0] = (short)f2bf((v.x - mean) * rstd * gv.x + bv.x);
  o[1] = (short)f2bf((v.y - mean) * rstd * gv.y + bv.y);
  o[2] = (short)f2bf((v.z - mean) * rstd * gv.z + bv.z);
  o[3] = (short)f2bf((v.w - mean) * rstd * gv.w + bv.w);
  *(short4v*)(y + (size_t)r * DD + tid * 4) = o;
}

// ---------------------------------------------------------------------------
// Attention: QBLK=128. T14: ph1's V-tile prefetched into regs during ph0;
// raw barriers + counted vmcnt(2) keep the prefetch in flight.
// ---------------------------------------------------------------------------
__global__ __launch_bounds__(512, 2) void k_attn_mfma(
    const unsigned short* __restrict__ qbf, const unsigned short* __restrict__ kbf,
    const unsigned short* __restrict__ vbf, unsigned short* __restrict__ attn) {
  const int bh = blockIdx.y;
  const int b = bh >> 4, h = bh & 15;
  const int tid = threadIdx.x, wv = tid >> 6, lane = tid & 63;
  const int fr = lane & 15, fg = lane >> 4;
  const int bl0 = blockIdx.x * 128;

  __shared__ __align__(16) char Kl[16384];    // [128p][64d] swz rows of 128B
  __shared__ __align__(16) char Vt[16384];    // 2 chunks of [64 dd][64 p]
  __shared__ __align__(16) char Pl[32768];    // 8 waves x [16 l][128 p]

  const size_t qrow = ((size_t)(bl0 + wv * 16 + fr) * BB + b) * DD + h * HDD;
  bf16x8 qf0 = *(const bf16x8*)(qbf + qrow + fg * 8);
  bf16x8 qf1 = *(const bf16x8*)(qbf + qrow + 32 + fg * 8);

  f32x4 o[4];
#pragma unroll
  for (int dt = 0; dt < 4; ++dt) o[dt] = (f32x4){0.f, 0.f, 0.f, 0.f};
  float psum = 0.f;
  char* Pw = Pl + wv * 4096;

  const int p2 = tid >> 3, c8v = tid & 7;
  const size_t vbase = ((size_t)((2 * p2) * BB + b)) * DD + h * HDD + c8v * 8;
  // prologue: ph0 V loads -> regs
  bf16x8 va = *(const bf16x8*)(vbf + vbase);
  bf16x8 vb_ = *(const bf16x8*)(vbf + vbase + BB * DD);

#pragma unroll
  for (int ph = 0; ph < 2; ++ph) {
    if (ph == 1) {
      // PV(ph0) ds_reads consumed; raw barrier (V-prefetch stays in flight)
      asm volatile("s_waitcnt lgkmcnt(0)" ::: "memory");
      __builtin_amdgcn_s_barrier();
    }
    // K gll16 first (so counted vmcnt below targets exactly these)
#pragma unroll
    for (int j = 0; j < 2; ++j) {
      int u = tid + j * 512;
      int p = u >> 3, slot = u & 7;
      gll16(kbf + ((size_t)((ph * 128 + p) * BB + b)) * DD + h * HDD +
                8 * (slot ^ (p & 7)),
            Kl + u * 16);
    }
    // V LDS writes from regs (reg-dep wait covers the V loads)
    {
      int pl = (2 * p2) & 63, pc = p2 >> 5;
      char* base = Vt + pc * 8192;
#pragma unroll
      for (int i = 0; i < 8; ++i) {
        int dd = c8v * 8 + i;
        unsigned int packed = (unsigned int)(unsigned short)va[i] |
                              ((unsigned int)(unsigned short)vb_[i] << 16);
        *(unsigned int*)(base + dd * 128 +
            ((((pl >> 3) ^ (dd & 7) ^ (dd >> 3)) & 7) << 4) + ((pl & 7) << 1)) = packed;
      }
    }
    bf16x8 van, vbn;
    if (ph == 0) {   // prefetch ph1 V (rows +128)
      van = *(const bf16x8*)(vbf + vbase + (size_t)128 * BB * DD);
      vbn = *(const bf16x8*)(vbf + vbase + (size_t)129 * BB * DD);
    }
    asm volatile("s_waitcnt lgkmcnt(0)" ::: "memory");
    if (ph == 0) {
      asm volatile("s_waitcnt vmcnt(2)" ::: "memory");   // K done, V-prefetch flying
    } else {
      asm volatile("s_waitcnt vmcnt(0)" ::: "memory");   // K done (nothing else)
    }
    __builtin_amdgcn_s_barrier();
    __builtin_amdgcn_sched_barrier(0);

    f32x4 s[8];
    __builtin_amdgcn_s_setprio(1);
#pragma unroll
    for (int pt = 0; pt < 8; ++pt) {
      int pr = pt * 16 + fr;
      bf16x8 a0 = *(const bf16x8*)(Kl + pr * 128 + ((fg ^ (pr & 7)) << 4));
      bf16x8 a1 = *(const bf16x8*)(Kl + pr * 128 + (((4 + fg) ^ (pr & 7)) << 4));
      f32x4 acc = (f32x4){0.f, 0.f, 0.f, 0.f};
      acc = MFMA16(a0, qf0, acc);
      acc = MFMA16(a1, qf1, acc);
      s[pt] = acc;
    }
    __builtin_amdgcn_s_setprio(0);

#pragma unroll
    for (int pt = 0; pt < 8; ++pt) {
      float e0 = __expf(s[pt][0]), e1 = __expf(s[pt][1]);
      float e2 = __expf(s[pt][2]), e3 = __expf(s[pt][3]);
      psum += (e0 + e1) + (e2 + e3);
      short4v pk;
      pk[0] = (short)f2bf(e0); pk[1] = (short)f2bf(e1);
      pk[2] = (short)f2bf(e2); pk[3] = (short)f2bf(e3);
      int pbyte = (pt * 16 + fg * 4) * 2;
      int slot = pbyte >> 4, rem = pbyte & 15;
      *(short4v*)(Pw + fr * 256 + ((slot ^ (fr & 7)) << 4) + rem) = pk;
    }
    asm volatile("s_waitcnt lgkmcnt(0)" ::: "memory");
    __builtin_amdgcn_sched_barrier(0);

    __builtin_amdgcn_s_setprio(1);
#pragma unroll
    for (int kc = 0; kc < 4; ++kc) {
      int slot = kc * 4 + fg;
      bf16x8 pa = *(const bf16x8*)(Pw + fr * 256 + ((slot ^ (fr & 7)) << 4));
      int sl2 = (kc & 1) * 4 + fg;
#pragma unroll
      for (int dt = 0; dt < 4; ++dt) {
        int dd = dt * 16 + fr;
        bf16x8 vbr = *(const bf16x8*)(Vt + (kc >> 1) * 8192 + dd * 128 +
                     (((sl2 ^ (dd & 7) ^ (dd >> 3)) & 7) << 4));
        o[dt] = MFMA16(pa, vbr, o[dt]);
      }
    }
    __builtin_amdgcn_s_setprio(0);

    if (ph == 0) { va = van; vb_ = vbn; }
  }

  psum += __shfl_xor(psum, 16);
  psum += __shfl_xor(psum, 32);

#pragma unroll
  for (int r = 0; r < 4; ++r) {
    int lloc = fg * 4 + r;
    float inv = 1.f / __shfl(psum, lloc);
    unsigned short* op = attn +
        ((size_t)(bl0 + wv * 16 + lloc) * BB + b) * DD + h * HDD;
#pragma unroll
    for (int dt = 0; dt < 4; ++dt)
      op[dt * 16 + fr] = f2bf(o[dt][r] * inv);
  }
}

extern "C" void kernel_launch(void* const* d_in, const int* in_sizes, int n_in,
                              void* d_out, int out_size, void* d_ws, size_t ws_size,
                              hipStream_t stream) {
  const float* query   = (const float*)d_in[0];
  const float* q_w     = (const float*)d_in[1];
  const float* q_b     = (const float*)d_in[2];
  const float* k_w     = (const float*)d_in[3];
  const float* k_b     = (const float*)d_in[4];
  const float* v_w     = (const float*)d_in[5];
  const float* v_b     = (const float*)d_in[6];
  const float* e_weight= (const float*)d_in[7];
  const float* e_out_w = (const float*)d_in[8];
  const float* e_out_b = (const float*)d_in[9];
  const float* ln_g    = (const float*)d_in[10];
  const float* ln_b    = (const float*)d_in[11];
  const float* out_w   = (const float*)d_in[12];
  const float* out_b   = (const float*)d_in[13];
  float* out = (float*)d_out;

  char* w = (char*)d_ws;
  unsigned short* parts   = (unsigned short*)w;                 // 32 MB, dead after reduce
  unsigned short* q_bf    = (unsigned short*)w;                 // 32 MB (alias, after reduce)
  unsigned short* attn_bf = (unsigned short*)(w + (32u << 20)); // 32 MB
  unsigned short* query_bf= (unsigned short*)(w + (64u << 20)); // 32 MB
  unsigned short* kv_raw  = (unsigned short*)(w + (96u << 20)); // 2 MB
  float* kv_eo            = (float*)(w + (98u << 20));          // 4 MB
  unsigned short* kv_ln   = (unsigned short*)(w + (102u << 20));// 2 MB
  unsigned short* k_buf   = (unsigned short*)(w + (104u << 20));// 2 MB
  unsigned short* v_buf   = (unsigned short*)(w + (106u << 20));// 2 MB
  unsigned short* wq  = (unsigned short*)(w + (108u << 20));
  unsigned short* wk  = (unsigned short*)(w + (110u << 20));
  unsigned short* wv_ = (unsigned short*)(w + (112u << 20));
  unsigned short* weo = (unsigned short*)(w + (114u << 20));
  unsigned short* wo  = (unsigned short*)(w + (116u << 20));
  unsigned short* ewb = (unsigned short*)(w + (118u << 20));    // 0.5 MB

  k_cvt_w<<<2688, 256, 0, stream>>>(q_w, k_w, v_w, e_out_w, out_w, e_weight,
                                    wq, wk, wv_, weo, wo, ewb);

  k_compress_mfma<<<dim3(64, LC), 256, 0, stream>>>(query, ewb, query_bf, parts);
  k_reduce<<<512, 256, 0, stream>>>(parts, kv_raw);
  k_gemm_mfma<2, float><<<dim3(8, 8), 256, 0, stream>>>(kv_raw, weo, e_out_b, e_weight, kv_eo);
  k_ln<<<PP * BB, 256, 0, stream>>>(kv_eo, ln_g, ln_b, kv_ln);
  k_gemm256<1, unsigned short><<<dim3(64, 4), 512, 0, stream>>>(query_bf, wq, q_b, q_bf);
  k_gemm_kv<<<dim3(8, 8, 2), 256, 0, stream>>>(kv_ln, wk, wv_, k_b, v_b, k_buf, v_buf);
  k_attn_mfma<<<dim3(32, 64), 512, 0, stream>>>(q_bf, k_buf, v_buf, attn_bf);
  k_gemm256<0, float><<<dim3(64, 4), 512, 0, stream>>>(attn_bf, wo, out_b, out);
}

// Round 14
// 203.353 us; speedup vs baseline: 1.0584x; 1.0438x over previous
//
#include <hip/hip_runtime.h>
#include <hip/hip_bf16.h>
#include <cstdint>
#include <cstddef>

#define LL 4096
#define BB 4
#define DD 1024
#define HH 16
#define PP 256
#define HDD 64
#define LC 8
#define LCHUNK 512

constexpr float kScaling = 0.125f;   // HD^-0.5
constexpr float kEps = 1e-5f;

typedef __attribute__((ext_vector_type(8))) short bf16x8;   // 8 bf16 = 4 VGPR
typedef __attribute__((ext_vector_type(4))) short short4v;
typedef __attribute__((ext_vector_type(4))) float f32x4;

#define MFMA16(a, b, c) __builtin_amdgcn_mfma_f32_16x16x32_bf16((a), (b), (c), 0, 0, 0)

__device__ __forceinline__ unsigned short f2bf(float f) {
  unsigned int u = __builtin_bit_cast(unsigned int, f);
  u += 0x7FFFu + ((u >> 16) & 1u);           // round-to-nearest-even
  return (unsigned short)(u >> 16);
}
__device__ __forceinline__ float bf2f(unsigned short u) {
  return __builtin_bit_cast(float, ((unsigned int)u) << 16);
}

__device__ __forceinline__ void gll16(const void* g, void* l) {
  __builtin_amdgcn_global_load_lds(
      (const __attribute__((address_space(1))) unsigned int*)g,
      (__attribute__((address_space(3))) unsigned int*)l, 16, 0, 0);
}

// ---------------------------------------------------------------------------
// Weights-only fp32 -> bf16 convert.
// ---------------------------------------------------------------------------
__global__ __launch_bounds__(256) void k_cvt_w(
    const float* __restrict__ w0, const float* __restrict__ w1,
    const float* __restrict__ w2, const float* __restrict__ w3,
    const float* __restrict__ w4, const float* __restrict__ w5,
    unsigned short* __restrict__ d0, unsigned short* __restrict__ d1,
    unsigned short* __restrict__ d2, unsigned short* __restrict__ d3,
    unsigned short* __restrict__ d4, unsigned short* __restrict__ d5) {
  int i = blockIdx.x * 256 + threadIdx.x;
  int w = i >> 17, off = i & 131071;
  const float* src; unsigned short* dst;
  if (w == 0) { src = w0; dst = d0; }
  else if (w == 1) { src = w1; dst = d1; }
  else if (w == 2) { src = w2; dst = d2; }
  else if (w == 3) { src = w3; dst = d3; }
  else if (w == 4) { src = w4; dst = d4; }
  else { if (off >= 32768) return; src = w5; dst = d5; }
  const float4* s = (const float4*)(src + (size_t)off * 8);
  float4 a = s[0], b = s[1];
  bf16x8 o;
  o[0] = f2bf(a.x); o[1] = f2bf(a.y); o[2] = f2bf(a.z); o[3] = f2bf(a.w);
  o[4] = f2bf(b.x); o[5] = f2bf(b.y); o[6] = f2bf(b.z); o[7] = f2bf(b.w);
  *(bf16x8*)(dst + (size_t)off * 8) = o;
}

// ---------------------------------------------------------------------------
// Compress (MFMA) + inline query cvt. LC=8: 512 blocks = exactly 2/CU
// (3 fit in LDS) -> all blocks co-resident, no tail round.
// ---------------------------------------------------------------------------
__global__ __launch_bounds__(256) void k_compress_mfma(
    const float* __restrict__ q32, const unsigned short* __restrict__ ewbf,
    unsigned short* __restrict__ qbf_out, unsigned short* __restrict__ parts) {
  const int bh = blockIdx.x, lc = blockIdx.y;
  const int b = bh >> 4, h = bh & 15;
  const int tid = threadIdx.x, wv = tid >> 6, lane = tid & 63;
  const int fr = lane & 15, fg = lane >> 4;

  __shared__ __align__(16) char Xl[8192];    // [l][d] rows of 128B
  __shared__ __align__(16) char Xtl[8192];   // [d][l]
  __shared__ __align__(16) char Pl[32768];   // [p][l] rows of 128B

  bf16x8 ef[4][2];
#pragma unroll
  for (int pt = 0; pt < 4; ++pt)
#pragma unroll
    for (int kc = 0; kc < 2; ++kc)
      ef[pt][kc] = *(const bf16x8*)(ewbf +
          (size_t)((h * PP + wv * 64 + pt * 16 + fr) * HDD) + kc * 32 + fg * 8);

  f32x4 acc[4][4];
#pragma unroll
  for (int i = 0; i < 4; ++i)
#pragma unroll
    for (int j = 0; j < 4; ++j) acc[i][j] = (f32x4){0.f, 0.f, 0.f, 0.f};

  const int l0 = lc * LCHUNK;
  for (int t = 0; t < LCHUNK / 64; ++t) {
    __syncthreads();
    {
      int l2 = tid >> 3, c8 = tid & 7;
      int l = 2 * l2;
      size_t rowbase = ((size_t)(l0 + t * 64 + l) * BB + b) * DD + h * HDD + c8 * 8;
      const float* xp = q32 + rowbase;
      float4 a0 = *(const float4*)xp;
      float4 a1 = *(const float4*)(xp + 4);
      float4 b0 = *(const float4*)(xp + BB * DD);
      float4 b1 = *(const float4*)(xp + BB * DD + 4);
      bf16x8 v0, v1;
      v0[0] = f2bf(a0.x); v0[1] = f2bf(a0.y); v0[2] = f2bf(a0.z); v0[3] = f2bf(a0.w);
      v0[4] = f2bf(a1.x); v0[5] = f2bf(a1.y); v0[6] = f2bf(a1.z); v0[7] = f2bf(a1.w);
      v1[0] = f2bf(b0.x); v1[1] = f2bf(b0.y); v1[2] = f2bf(b0.z); v1[3] = f2bf(b0.w);
      v1[4] = f2bf(b1.x); v1[5] = f2bf(b1.y); v1[6] = f2bf(b1.z); v1[7] = f2bf(b1.w);
      // global bf16 copy for q-proj (each (l,b,h,d) written exactly once)
      *(bf16x8*)(qbf_out + rowbase) = v0;
      *(bf16x8*)(qbf_out + rowbase + BB * DD) = v1;
      // LDS tiles
      *(bf16x8*)(Xl + l * 128 + ((c8 ^ (l & 7)) << 4)) = v0;
      *(bf16x8*)(Xl + (l + 1) * 128 + ((c8 ^ ((l + 1) & 7)) << 4)) = v1;
#pragma unroll
      for (int i = 0; i < 8; ++i) {
        int dd = c8 * 8 + i;
        unsigned int packed = (unsigned int)(unsigned short)v0[i] |
                              ((unsigned int)(unsigned short)v1[i] << 16);
        *(unsigned int*)(Xtl + dd * 128 +
            ((((l >> 3) ^ (dd & 7) ^ (dd >> 3)) & 7) << 4) + ((l & 7) << 1)) = packed;
      }
    }
    __syncthreads();
#pragma unroll
    for (int lt = 0; lt < 4; ++lt) {
      int rl = lt * 16 + fr;
      bf16x8 xa0 = *(const bf16x8*)(Xl + rl * 128 + (((0 + fg) ^ (rl & 7)) << 4));
      bf16x8 xa1 = *(const bf16x8*)(Xl + rl * 128 + (((4 + fg) ^ (rl & 7)) << 4));
#pragma unroll
      for (int pt = 0; pt < 4; ++pt) {
        f32x4 s = (f32x4){0.f, 0.f, 0.f, 0.f};
        s = MFMA16(xa0, ef[pt][0], s);
        s = MFMA16(xa1, ef[pt][1], s);
        short4v pk;
#pragma unroll
        for (int r = 0; r < 4; ++r)
          pk[r] = (short)f2bf(fmaxf(s[r] * kScaling, 0.f));
        int p = wv * 64 + pt * 16 + fr;
        int lbase = lt * 16 + fg * 4;
        int slot = lbase >> 3;
        *(short4v*)(Pl + p * 128 + ((slot ^ (p & 7)) << 4) + ((lbase & 7) << 1)) = pk;
      }
    }
    asm volatile("s_waitcnt lgkmcnt(0)" ::: "memory");
    __builtin_amdgcn_sched_barrier(0);
#pragma unroll
    for (int kc = 0; kc < 2; ++kc) {
      bf16x8 pa[4], xb[4];
#pragma unroll
      for (int pt = 0; pt < 4; ++pt) {
        int p = wv * 64 + pt * 16 + fr;
        pa[pt] = *(const bf16x8*)(Pl + p * 128 + (((kc * 4 + fg) ^ (p & 7)) << 4));
      }
#pragma unroll
      for (int dt = 0; dt < 4; ++dt) {
        int dd = dt * 16 + fr;
        xb[dt] = *(const bf16x8*)(Xtl + dd * 128 +
                  ((((kc * 4 + fg) ^ (dd & 7) ^ (dd >> 3)) & 7) << 4));
      }
#pragma unroll
      for (int pt = 0; pt < 4; ++pt)
#pragma unroll
        for (int dt = 0; dt < 4; ++dt)
          acc[pt][dt] = MFMA16(pa[pt], xb[dt], acc[pt][dt]);
    }
  }
  unsigned short* op = parts + (size_t)(lc * 64 + bh) * PP * HDD;
#pragma unroll
  for (int pt = 0; pt < 4; ++pt)
#pragma unroll
    for (int dt = 0; dt < 4; ++dt)
#pragma unroll
      for (int r = 0; r < 4; ++r) {
        int p = wv * 64 + pt * 16 + fg * 4 + r;
        int dd = dt * 16 + fr;
        op[(size_t)p * HDD + dd] = f2bf(acc[pt][dt][r]);
      }
}

// Sum LC bf16 partials -> kv_raw bf16 as (P,B,D); vectorized x8.
__global__ __launch_bounds__(256) void k_reduce(const unsigned short* __restrict__ parts,
                                                unsigned short* __restrict__ kv_raw_bf) {
  int u = blockIdx.x * 256 + threadIdx.x;     // 131072 units of 8 elems
  size_t off = (size_t)u * 8;
  float s[8] = {0.f, 0.f, 0.f, 0.f, 0.f, 0.f, 0.f, 0.f};
#pragma unroll
  for (int lcc = 0; lcc < LC; ++lcc) {
    bf16x8 v = *(const bf16x8*)(parts + (size_t)lcc * (64 * PP * HDD) + off);
#pragma unroll
    for (int j = 0; j < 8; ++j) s[j] += bf2f((unsigned short)v[j]);
  }
  int i = (int)off;
  int d = i & 63, p = (i >> 6) & 255, bh = i >> 14;
  int b = bh >> 4, h = bh & 15;
  bf16x8 o;
#pragma unroll
  for (int j = 0; j < 8; ++j) o[j] = (short)f2bf(s[j]);
  *(bf16x8*)(kv_raw_bf + (size_t)(p * BB + b) * DD + h * HDD + d) = o;
}

// ---------------------------------------------------------------------------
// 128x128 GEMM body (small P=1024-row GEMMs).
// ---------------------------------------------------------------------------
template <int MODE, typename OUTT>
__device__ __forceinline__ void gemm_body(
    const unsigned short* __restrict__ A, const unsigned short* __restrict__ W,
    const float* __restrict__ bias, const float* __restrict__ ew,
    OUTT* __restrict__ C, int m0, int n0, char* Al, char* Bl) {
  const int tid = threadIdx.x;
  const int wv = tid >> 6, lane = tid & 63;
  const int fr = lane & 15, fg = lane >> 4;
  const int wr = wv >> 1, wc = wv & 1;

  f32x4 acc[4][4];
#pragma unroll
  for (int i = 0; i < 4; ++i)
#pragma unroll
    for (int j = 0; j < 4; ++j) acc[i][j] = (f32x4){0.f, 0.f, 0.f, 0.f};

  for (int k0 = 0; k0 < DD; k0 += 64) {
    __syncthreads();
#pragma unroll
    for (int j = 0; j < 4; ++j) {
      int u = tid + j * 256;
      int row = u >> 3, slot = u & 7;
      size_t gcol = (size_t)(k0 + 8 * (slot ^ (row & 7)));
      gll16(A + (size_t)(m0 + row) * DD + gcol, Al + u * 16);
      gll16(W + (size_t)(n0 + row) * DD + gcol, Bl + u * 16);
    }
    __syncthreads();
#pragma unroll
    for (int kc = 0; kc < 2; ++kc) {
      bf16x8 af[4], bfr[4];
#pragma unroll
      for (int mt = 0; mt < 4; ++mt) {
        int r = wr * 64 + mt * 16 + fr;
        af[mt] = *(const bf16x8*)(Al + r * 128 + (((kc * 4 + fg) ^ (r & 7)) << 4));
      }
#pragma unroll
      for (int nt = 0; nt < 4; ++nt) {
        int r = wc * 64 + nt * 16 + fr;
        bfr[nt] = *(const bf16x8*)(Bl + r * 128 + (((kc * 4 + fg) ^ (r & 7)) << 4));
      }
#pragma unroll
      for (int mt = 0; mt < 4; ++mt)
#pragma unroll
        for (int nt = 0; nt < 4; ++nt)
          acc[mt][nt] = MFMA16(af[mt], bfr[nt], acc[mt][nt]);
    }
  }

  float bs[4];
#pragma unroll
  for (int nt = 0; nt < 4; ++nt) bs[nt] = bias[n0 + wc * 64 + nt * 16 + fr];
#pragma unroll
  for (int mt = 0; mt < 4; ++mt)
#pragma unroll
    for (int nt = 0; nt < 4; ++nt) {
      int n = n0 + wc * 64 + nt * 16 + fr;
#pragma unroll
      for (int r = 0; r < 4; ++r) {
        int m = m0 + wr * 64 + mt * 16 + fg * 4 + r;
        float v = acc[mt][nt][r] + bs[nt];
        if (MODE == 1) v *= kScaling;
        if (MODE == 2) {
          int p = m >> 2, hh = n >> 6, d2 = n & 63;
          v += ew[(size_t)((hh << 8) + p) * HDD + d2];
        }
        if constexpr (sizeof(OUTT) == 2)
          C[(size_t)m * DD + n] = (OUTT)f2bf(v);
        else
          C[(size_t)m * DD + n] = v;
      }
    }
}

template <int MODE, typename OUTT>
__global__ __launch_bounds__(256) void k_gemm_mfma(
    const unsigned short* __restrict__ A, const unsigned short* __restrict__ W,
    const float* __restrict__ bias, const float* __restrict__ ew,
    OUTT* __restrict__ C) {
  __shared__ __align__(16) char Al[16384];
  __shared__ __align__(16) char Bl[16384];
  gemm_body<MODE, OUTT>(A, W, bias, ew, C, blockIdx.x * 128, blockIdx.y * 128, Al, Bl);
}

// K and V projections in one launch (blockIdx.z selects).
__global__ __launch_bounds__(256) void k_gemm_kv(
    const unsigned short* __restrict__ A,
    const unsigned short* __restrict__ Wk, const unsigned short* __restrict__ Wv,
    const float* __restrict__ kb, const float* __restrict__ vb,
    unsigned short* __restrict__ Ck, unsigned short* __restrict__ Cv) {
  __shared__ __align__(16) char Al[16384];
  __shared__ __align__(16) char Bl[16384];
  if (blockIdx.z == 0)
    gemm_body<0, unsigned short>(A, Wk, kb, nullptr, Ck,
                                 blockIdx.x * 128, blockIdx.y * 128, Al, Bl);
  else
    gemm_body<0, unsigned short>(A, Wv, vb, nullptr, Cv,
                                 blockIdx.x * 128, blockIdx.y * 128, Al, Bl);
}

// ---------------------------------------------------------------------------
// 256x256 GEMM, minimal-barrier schedule (unchanged).
// ---------------------------------------------------------------------------
template <int MODE, typename OUTT>
__global__ __launch_bounds__(512, 2) void k_gemm256(
    const unsigned short* __restrict__ A, const unsigned short* __restrict__ W,
    const float* __restrict__ bias, OUTT* __restrict__ C) {
  __shared__ __align__(16) char lds[131072];
  const int tid = threadIdx.x;
  const int wv = tid >> 6, lane = tid & 63;
  const int fr = lane & 15, fg = lane >> 4;
  const int wm = wv >> 2, wn = wv & 3;
  const int m0 = blockIdx.x * 256, n0 = blockIdx.y * 256;
  const int srow = tid >> 2, sslot = tid & 3;

  auto stageHalf = [&](const unsigned short* __restrict__ G, int g0, int colbase,
                       int dstBase) {
#pragma unroll
    for (int j = 0; j < 2; ++j) {
      int row = srow + j * 128;
      int gs = sslot ^ ((row >> 1) & 3);
      gll16(G + (size_t)(g0 + row) * DD + colbase + gs * 8,
            lds + dstBase + (tid + j * 512) * 16);
    }
  };
  auto rdA = [&](int mf, int kc, int cb) -> bf16x8 {
    int r = wm * 128 + mf * 16 + fr;
    return *(const bf16x8*)(lds + cb + kc * 16384 + r * 64 +
                            ((fg ^ ((r >> 1) & 3)) << 4));
  };
  auto rdB = [&](int nf, int kc, int cb) -> bf16x8 {
    int r = wn * 64 + nf * 16 + fr;
    return *(const bf16x8*)(lds + cb + 32768 + kc * 16384 + r * 64 +
                            ((fg ^ ((r >> 1) & 3)) << 4));
  };

  f32x4 acc[8][4];
#pragma unroll
  for (int i = 0; i < 8; ++i)
#pragma unroll
    for (int j = 0; j < 4; ++j) acc[i][j] = (f32x4){0.f, 0.f, 0.f, 0.f};
  bf16x8 a[8], b[4];

  stageHalf(A, m0, 0, 0);
  stageHalf(W, n0, 0, 32768);
  stageHalf(A, m0, 32, 16384);
  stageHalf(W, n0, 32, 32768 + 16384);
  stageHalf(A, m0, 64, 65536);
  stageHalf(W, n0, 64, 65536 + 32768);
  asm volatile("s_waitcnt vmcnt(4)" ::: "memory");   // tile0 arrived
  __builtin_amdgcn_s_barrier();

  const int NT = DD / 64;   // 16
  for (int t = 0; t < NT; ++t) {
    const int cb = (t & 1) << 16;
    const int nb = cb ^ 65536;
    const int k1 = (t + 1) * 64, k2 = (t + 2) * 64;

    // ---- half 1: kc0 (all mf), stage t+1.kc1 into nb
#pragma unroll
    for (int i = 0; i < 8; ++i) a[i] = rdA(i, 0, cb);
#pragma unroll
    for (int i = 0; i < 4; ++i) b[i] = rdB(i, 0, cb);
    if (t + 1 < NT) {
      stageHalf(A, m0, k1 + 32, nb + 16384);
      stageHalf(W, n0, k1 + 32, nb + 32768 + 16384);
    }
    asm volatile("s_waitcnt lgkmcnt(0)" ::: "memory");
    __builtin_amdgcn_sched_barrier(0);
    __builtin_amdgcn_s_setprio(1);
#pragma unroll
    for (int mf = 0; mf < 8; ++mf)
#pragma unroll
      for (int nf = 0; nf < 4; ++nf)
        acc[mf][nf] = MFMA16(a[mf], b[nf], acc[mf][nf]);
    __builtin_amdgcn_s_setprio(0);
    __builtin_amdgcn_s_barrier();   // mid: kc0 reads done across waves

    // ---- half 2: kc1 (all mf), stage t+2.kc0 into cb
#pragma unroll
    for (int i = 0; i < 8; ++i) a[i] = rdA(i, 1, cb);
#pragma unroll
    for (int i = 0; i < 4; ++i) b[i] = rdB(i, 1, cb);
    if (t + 2 < NT) {
      stageHalf(A, m0, k2, cb);
      stageHalf(W, n0, k2, cb + 32768);
    }
    asm volatile("s_waitcnt lgkmcnt(0)" ::: "memory");
    __builtin_amdgcn_sched_barrier(0);
    __builtin_amdgcn_s_setprio(1);
#pragma unroll
    for (int mf = 0; mf < 8; ++mf)
#pragma unroll
      for (int nf = 0; nf < 4; ++nf)
        acc[mf][nf] = MFMA16(a[mf], b[nf], acc[mf][nf]);
    __builtin_amdgcn_s_setprio(0);
    if (t + 2 < NT) {
      asm volatile("s_waitcnt vmcnt(4)" ::: "memory");   // t+1 fully arrived
    } else if (t + 1 < NT) {
      asm volatile("s_waitcnt vmcnt(0)" ::: "memory");   // drain for last tile
    }
    __builtin_amdgcn_s_barrier();   // end of tile
  }

  float bs[4];
#pragma unroll
  for (int nf = 0; nf < 4; ++nf) bs[nf] = bias[n0 + wn * 64 + nf * 16 + fr];
#pragma unroll
  for (int mf = 0; mf < 8; ++mf)
#pragma unroll
    for (int nf = 0; nf < 4; ++nf) {
      int n = n0 + wn * 64 + nf * 16 + fr;
#pragma unroll
      for (int r = 0; r < 4; ++r) {
        int m = m0 + wm * 128 + mf * 16 + fg * 4 + r;
        float v = acc[mf][nf][r] + bs[nf];
        if (MODE == 1) v *= kScaling;
        if constexpr (sizeof(OUTT) == 2)
          C[(size_t)m * DD + n] = (OUTT)f2bf(v);
        else
          C[(size_t)m * DD + n] = v;
      }
    }
}

// LayerNorm over D=1024; fp32 in -> bf16 out. One block per row.
__global__ __launch_bounds__(256) void k_ln(const float* __restrict__ x,
                                            const float* __restrict__ g,
                                            const float* __restrict__ bb,
                                            unsigned short* __restrict__ y) {
  const int r = blockIdx.x;
  const int tid = threadIdx.x;
  const float* xr = x + (size_t)r * DD;
  float4 v = *(const float4*)(xr + tid * 4);
  float s1 = v.x + v.y + v.z + v.w;
  float s2 = v.x * v.x + v.y * v.y + v.z * v.z + v.w * v.w;
#pragma unroll
  for (int off = 32; off > 0; off >>= 1) {
    s1 += __shfl_down(s1, off);
    s2 += __shfl_down(s2, off);
  }
  __shared__ float w1[4], w2[4];
  if ((tid & 63) == 0) { w1[tid >> 6] = s1; w2[tid >> 6] = s2; }
  __syncthreads();
  float S1 = w1[0] + w1[1] + w1[2] + w1[3];
  float S2 = w2[0] + w2[1] + w2[2] + w2[3];
  float mean = S1 * (1.f / DD);
  float var = S2 * (1.f / DD) - mean * mean;
  float rstd = rsqrtf(var + kEps);
  float4 gv = *(const float4*)(g + tid * 4);
  float4 bv = *(const float4*)(bb + tid * 4);
  short4v o;
  o[0] = (short)f2bf((v.x - mean) * rstd * gv.x + bv.x);
  o[1] = (short)f2bf((v.y - mean) * rstd * gv.y + bv.y);
  o[2] = (short)f2bf((v.z - mean) * rstd * gv.z + bv.z);
  o[3] = (short)f2bf((v.w - mean) * rstd * gv.w + bv.w);
  *(short4v*)(y + (size_t)r * DD + tid * 4) = o;
}

// ---------------------------------------------------------------------------
// Attention: QBLK=128. T14: ph1's V-tile prefetched into regs during ph0;
// raw barriers + counted vmcnt(2) keep the prefetch in flight.
// ---------------------------------------------------------------------------
__global__ __launch_bounds__(512, 2) void k_attn_mfma(
    const unsigned short* __restrict__ qbf, const unsigned short* __restrict__ kbf,
    const unsigned short* __restrict__ vbf, unsigned short* __restrict__ attn) {
  const int bh = blockIdx.y;
  const int b = bh >> 4, h = bh & 15;
  const int tid = threadIdx.x, wv = tid >> 6, lane = tid & 63;
  const int fr = lane & 15, fg = lane >> 4;
  const int bl0 = blockIdx.x * 128;

  __shared__ __align__(16) char Kl[16384];    // [128p][64d] swz rows of 128B
  __shared__ __align__(16) char Vt[16384];    // 2 chunks of [64 dd][64 p]
  __shared__ __align__(16) char Pl[32768];    // 8 waves x [16 l][128 p]

  const size_t qrow = ((size_t)(bl0 + wv * 16 + fr) * BB + b) * DD + h * HDD;
  bf16x8 qf0 = *(const bf16x8*)(qbf + qrow + fg * 8);
  bf16x8 qf1 = *(const bf16x8*)(qbf + qrow + 32 + fg * 8);

  f32x4 o[4];
#pragma unroll
  for (int dt = 0; dt < 4; ++dt) o[dt] = (f32x4){0.f, 0.f, 0.f, 0.f};
  float psum = 0.f;
  char* Pw = Pl + wv * 4096;

  const int p2 = tid >> 3, c8v = tid & 7;
  const size_t vbase = ((size_t)((2 * p2) * BB + b)) * DD + h * HDD + c8v * 8;
  // prologue: ph0 V loads -> regs
  bf16x8 va = *(const bf16x8*)(vbf + vbase);
  bf16x8 vb_ = *(const bf16x8*)(vbf + vbase + BB * DD);

#pragma unroll
  for (int ph = 0; ph < 2; ++ph) {
    if (ph == 1) {
      // PV(ph0) ds_reads consumed; raw barrier (V-prefetch stays in flight)
      asm volatile("s_waitcnt lgkmcnt(0)" ::: "memory");
      __builtin_amdgcn_s_barrier();
    }
    // K gll16 first (so counted vmcnt below targets exactly these)
#pragma unroll
    for (int j = 0; j < 2; ++j) {
      int u = tid + j * 512;
      int p = u >> 3, slot = u & 7;
      gll16(kbf + ((size_t)((ph * 128 + p) * BB + b)) * DD + h * HDD +
                8 * (slot ^ (p & 7)),
            Kl + u * 16);
    }
    // V LDS writes from regs (reg-dep wait covers the V loads)
    {
      int pl = (2 * p2) & 63, pc = p2 >> 5;
      char* base = Vt + pc * 8192;
#pragma unroll
      for (int i = 0; i < 8; ++i) {
        int dd = c8v * 8 + i;
        unsigned int packed = (unsigned int)(unsigned short)va[i] |
                              ((unsigned int)(unsigned short)vb_[i] << 16);
        *(unsigned int*)(base + dd * 128 +
            ((((pl >> 3) ^ (dd & 7) ^ (dd >> 3)) & 7) << 4) + ((pl & 7) << 1)) = packed;
      }
    }
    bf16x8 van, vbn;
    if (ph == 0) {   // prefetch ph1 V (rows +128)
      van = *(const bf16x8*)(vbf + vbase + (size_t)128 * BB * DD);
      vbn = *(const bf16x8*)(vbf + vbase + (size_t)129 * BB * DD);
    }
    asm volatile("s_waitcnt lgkmcnt(0)" ::: "memory");
    if (ph == 0) {
      asm volatile("s_waitcnt vmcnt(2)" ::: "memory");   // K done, V-prefetch flying
    } else {
      asm volatile("s_waitcnt vmcnt(0)" ::: "memory");   // K done (nothing else)
    }
    __builtin_amdgcn_s_barrier();
    __builtin_amdgcn_sched_barrier(0);

    f32x4 s[8];
    __builtin_amdgcn_s_setprio(1);
#pragma unroll
    for (int pt = 0; pt < 8; ++pt) {
      int pr = pt * 16 + fr;
      bf16x8 a0 = *(const bf16x8*)(Kl + pr * 128 + ((fg ^ (pr & 7)) << 4));
      bf16x8 a1 = *(const bf16x8*)(Kl + pr * 128 + (((4 + fg) ^ (pr & 7)) << 4));
      f32x4 acc = (f32x4){0.f, 0.f, 0.f, 0.f};
      acc = MFMA16(a0, qf0, acc);
      acc = MFMA16(a1, qf1, acc);
      s[pt] = acc;
    }
    __builtin_amdgcn_s_setprio(0);

#pragma unroll
    for (int pt = 0; pt < 8; ++pt) {
      float e0 = __expf(s[pt][0]), e1 = __expf(s[pt][1]);
      float e2 = __expf(s[pt][2]), e3 = __expf(s[pt][3]);
      psum += (e0 + e1) + (e2 + e3);
      short4v pk;
      pk[0] = (short)f2bf(e0); pk[1] = (short)f2bf(e1);
      pk[2] = (short)f2bf(e2); pk[3] = (short)f2bf(e3);
      int pbyte = (pt * 16 + fg * 4) * 2;
      int slot = pbyte >> 4, rem = pbyte & 15;
      *(short4v*)(Pw + fr * 256 + ((slot ^ (fr & 7)) << 4) + rem) = pk;
    }
    asm volatile("s_waitcnt lgkmcnt(0)" ::: "memory");
    __builtin_amdgcn_sched_barrier(0);

    __builtin_amdgcn_s_setprio(1);
#pragma unroll
    for (int kc = 0; kc < 4; ++kc) {
      int slot = kc * 4 + fg;
      bf16x8 pa = *(const bf16x8*)(Pw + fr * 256 + ((slot ^ (fr & 7)) << 4));
      int sl2 = (kc & 1) * 4 + fg;
#pragma unroll
      for (int dt = 0; dt < 4; ++dt) {
        int dd = dt * 16 + fr;
        bf16x8 vbr = *(const bf16x8*)(Vt + (kc >> 1) * 8192 + dd * 128 +
                     (((sl2 ^ (dd & 7) ^ (dd >> 3)) & 7) << 4));
        o[dt] = MFMA16(pa, vbr, o[dt]);
      }
    }
    __builtin_amdgcn_s_setprio(0);

    if (ph == 0) { va = van; vb_ = vbn; }
  }

  psum += __shfl_xor(psum, 16);
  psum += __shfl_xor(psum, 32);

#pragma unroll
  for (int r = 0; r < 4; ++r) {
    int lloc = fg * 4 + r;
    float inv = 1.f / __shfl(psum, lloc);
    unsigned short* op = attn +
        ((size_t)(bl0 + wv * 16 + lloc) * BB + b) * DD + h * HDD;
#pragma unroll
    for (int dt = 0; dt < 4; ++dt)
      op[dt * 16 + fr] = f2bf(o[dt][r] * inv);
  }
}

extern "C" void kernel_launch(void* const* d_in, const int* in_sizes, int n_in,
                              void* d_out, int out_size, void* d_ws, size_t ws_size,
                              hipStream_t stream) {
  const float* query   = (const float*)d_in[0];
  const float* q_w     = (const float*)d_in[1];
  const float* q_b     = (const float*)d_in[2];
  const float* k_w     = (const float*)d_in[3];
  const float* k_b     = (const float*)d_in[4];
  const float* v_w     = (const float*)d_in[5];
  const float* v_b     = (const float*)d_in[6];
  const float* e_weight= (const float*)d_in[7];
  const float* e_out_w = (const float*)d_in[8];
  const float* e_out_b = (const float*)d_in[9];
  const float* ln_g    = (const float*)d_in[10];
  const float* ln_b    = (const float*)d_in[11];
  const float* out_w   = (const float*)d_in[12];
  const float* out_b   = (const float*)d_in[13];
  float* out = (float*)d_out;

  char* w = (char*)d_ws;
  unsigned short* parts   = (unsigned short*)w;                 // 16 MB, dead after reduce
  unsigned short* q_bf    = (unsigned short*)w;                 // 32 MB (alias, after reduce)
  unsigned short* attn_bf = (unsigned short*)(w + (32u << 20)); // 32 MB
  unsigned short* query_bf= (unsigned short*)(w + (64u << 20)); // 32 MB
  unsigned short* kv_raw  = (unsigned short*)(w + (96u << 20)); // 2 MB
  float* kv_eo            = (float*)(w + (98u << 20));          // 4 MB
  unsigned short* kv_ln   = (unsigned short*)(w + (102u << 20));// 2 MB
  unsigned short* k_buf   = (unsigned short*)(w + (104u << 20));// 2 MB
  unsigned short* v_buf   = (unsigned short*)(w + (106u << 20));// 2 MB
  unsigned short* wq  = (unsigned short*)(w + (108u << 20));
  unsigned short* wk  = (unsigned short*)(w + (110u << 20));
  unsigned short* wv_ = (unsigned short*)(w + (112u << 20));
  unsigned short* weo = (unsigned short*)(w + (114u << 20));
  unsigned short* wo  = (unsigned short*)(w + (116u << 20));
  unsigned short* ewb = (unsigned short*)(w + (118u << 20));    // 0.5 MB

  k_cvt_w<<<2688, 256, 0, stream>>>(q_w, k_w, v_w, e_out_w, out_w, e_weight,
                                    wq, wk, wv_, weo, wo, ewb);

  k_compress_mfma<<<dim3(64, LC), 256, 0, stream>>>(query, ewb, query_bf, parts);
  k_reduce<<<512, 256, 0, stream>>>(parts, kv_raw);
  k_gemm_mfma<2, float><<<dim3(8, 8), 256, 0, stream>>>(kv_raw, weo, e_out_b, e_weight, kv_eo);
  k_ln<<<PP * BB, 256, 0, stream>>>(kv_eo, ln_g, ln_b, kv_ln);
  k_gemm256<1, unsigned short><<<dim3(64, 4), 512, 0, stream>>>(query_bf, wq, q_b, q_bf);
  k_gemm_kv<<<dim3(8, 8, 2), 256, 0, stream>>>(kv_ln, wk, wv_, k_b, v_b, k_buf, v_buf);
  k_attn_mfma<<<dim3(32, 64), 512, 0, stream>>>(q_bf, k_buf, v_buf, attn_bf);
  k_gemm256<0, float><<<dim3(64, 4), 512, 0, stream>>>(attn_bf, wo, out_b, out);
}

// Round 16
// 199.615 us; speedup vs baseline: 1.0782x; 1.0187x over previous
//
#include <hip/hip_runtime.h>
#include <hip/hip_bf16.h>
#include <cstdint>
#include <cstddef>

#define LL 4096
#define BB 4
#define DD 1024
#define HH 16
#define PP 256
#define HDD 64
#define LC 8
#define LCHUNK 512

constexpr float kScaling = 0.125f;   // HD^-0.5
constexpr float kEps = 1e-5f;

typedef __attribute__((ext_vector_type(8))) short bf16x8;   // 8 bf16 = 4 VGPR
typedef __attribute__((ext_vector_type(4))) short short4v;
typedef __attribute__((ext_vector_type(4))) float f32x4;

#define MFMA16(a, b, c) __builtin_amdgcn_mfma_f32_16x16x32_bf16((a), (b), (c), 0, 0, 0)

__device__ __forceinline__ unsigned short f2bf(float f) {
  unsigned int u = __builtin_bit_cast(unsigned int, f);
  u += 0x7FFFu + ((u >> 16) & 1u);           // round-to-nearest-even
  return (unsigned short)(u >> 16);
}
// paired RNE cast -> compiler emits v_cvt_pk_bf16_f32 (1 op / 2 elems)
__device__ __forceinline__ unsigned int f2bf2(float lo, float hi) {
  __hip_bfloat162 h = __float22bfloat162_rn(make_float2(lo, hi));
  unsigned int u;
  __builtin_memcpy(&u, &h, 4);
  return u;
}
__device__ __forceinline__ float bf2f(unsigned short u) {
  return __builtin_bit_cast(float, ((unsigned int)u) << 16);
}

__device__ __forceinline__ void gll16(const void* g, void* l) {
  __builtin_amdgcn_global_load_lds(
      (const __attribute__((address_space(1))) unsigned int*)g,
      (__attribute__((address_space(3))) unsigned int*)l, 16, 0, 0);
}

// ---------------------------------------------------------------------------
// Weights-only fp32 -> bf16 convert (pk casts).
// ---------------------------------------------------------------------------
__global__ __launch_bounds__(256) void k_cvt_w(
    const float* __restrict__ w0, const float* __restrict__ w1,
    const float* __restrict__ w2, const float* __restrict__ w3,
    const float* __restrict__ w4, const float* __restrict__ w5,
    unsigned short* __restrict__ d0, unsigned short* __restrict__ d1,
    unsigned short* __restrict__ d2, unsigned short* __restrict__ d3,
    unsigned short* __restrict__ d4, unsigned short* __restrict__ d5) {
  int i = blockIdx.x * 256 + threadIdx.x;
  int w = i >> 17, off = i & 131071;
  const float* src; unsigned short* dst;
  if (w == 0) { src = w0; dst = d0; }
  else if (w == 1) { src = w1; dst = d1; }
  else if (w == 2) { src = w2; dst = d2; }
  else if (w == 3) { src = w3; dst = d3; }
  else if (w == 4) { src = w4; dst = d4; }
  else { if (off >= 32768) return; src = w5; dst = d5; }
  const float4* s = (const float4*)(src + (size_t)off * 8);
  float4 a = s[0], b = s[1];
  uint4 o;
  o.x = f2bf2(a.x, a.y); o.y = f2bf2(a.z, a.w);
  o.z = f2bf2(b.x, b.y); o.w = f2bf2(b.z, b.w);
  *(uint4*)(dst + (size_t)off * 8) = o;
}

// ---------------------------------------------------------------------------
// Compress (MFMA) + inline query cvt (pk casts). LC=8: 512 blocks = 2/CU.
// ---------------------------------------------------------------------------
__global__ __launch_bounds__(256) void k_compress_mfma(
    const float* __restrict__ q32, const unsigned short* __restrict__ ewbf,
    unsigned short* __restrict__ qbf_out, unsigned short* __restrict__ parts) {
  const int bh = blockIdx.x, lc = blockIdx.y;
  const int b = bh >> 4, h = bh & 15;
  const int tid = threadIdx.x, wv = tid >> 6, lane = tid & 63;
  const int fr = lane & 15, fg = lane >> 4;

  __shared__ __align__(16) char Xl[8192];    // [l][d] rows of 128B
  __shared__ __align__(16) char Xtl[8192];   // [d][l]
  __shared__ __align__(16) char Pl[32768];   // [p][l] rows of 128B

  bf16x8 ef[4][2];
#pragma unroll
  for (int pt = 0; pt < 4; ++pt)
#pragma unroll
    for (int kc = 0; kc < 2; ++kc)
      ef[pt][kc] = *(const bf16x8*)(ewbf +
          (size_t)((h * PP + wv * 64 + pt * 16 + fr) * HDD) + kc * 32 + fg * 8);

  f32x4 acc[4][4];
#pragma unroll
  for (int i = 0; i < 4; ++i)
#pragma unroll
    for (int j = 0; j < 4; ++j) acc[i][j] = (f32x4){0.f, 0.f, 0.f, 0.f};

  const int l0 = lc * LCHUNK;
  for (int t = 0; t < LCHUNK / 64; ++t) {
    __syncthreads();
    {
      int l2 = tid >> 3, c8 = tid & 7;
      int l = 2 * l2;
      size_t rowbase = ((size_t)(l0 + t * 64 + l) * BB + b) * DD + h * HDD + c8 * 8;
      const float* xp = q32 + rowbase;
      float4 a0 = *(const float4*)xp;
      float4 a1 = *(const float4*)(xp + 4);
      float4 b0 = *(const float4*)(xp + BB * DD);
      float4 b1 = *(const float4*)(xp + BB * DD + 4);
      unsigned int W[4], U[4];
      W[0] = f2bf2(a0.x, a0.y); W[1] = f2bf2(a0.z, a0.w);
      W[2] = f2bf2(a1.x, a1.y); W[3] = f2bf2(a1.z, a1.w);
      U[0] = f2bf2(b0.x, b0.y); U[1] = f2bf2(b0.z, b0.w);
      U[2] = f2bf2(b1.x, b1.y); U[3] = f2bf2(b1.z, b1.w);
      uint4 V0 = {W[0], W[1], W[2], W[3]};
      uint4 V1 = {U[0], U[1], U[2], U[3]};
      // global bf16 copy for q-proj
      *(uint4*)(qbf_out + rowbase) = V0;
      *(uint4*)(qbf_out + rowbase + BB * DD) = V1;
      // LDS tiles
      *(uint4*)(Xl + l * 128 + ((c8 ^ (l & 7)) << 4)) = V0;
      *(uint4*)(Xl + (l + 1) * 128 + ((c8 ^ ((l + 1) & 7)) << 4)) = V1;
      // Xtl transpose: cross-pack (v0[i], v1[i]) pairs from packed words
#pragma unroll
      for (int j = 0; j < 4; ++j) {
        int dd0 = c8 * 8 + 2 * j, dd1 = dd0 + 1;
        unsigned int pe = (W[j] & 0xFFFFu) | (U[j] << 16);
        unsigned int po = (W[j] >> 16) | (U[j] & 0xFFFF0000u);
        *(unsigned int*)(Xtl + dd0 * 128 +
            ((((l >> 3) ^ (dd0 & 7) ^ (dd0 >> 3)) & 7) << 4) + ((l & 7) << 1)) = pe;
        *(unsigned int*)(Xtl + dd1 * 128 +
            ((((l >> 3) ^ (dd1 & 7) ^ (dd1 >> 3)) & 7) << 4) + ((l & 7) << 1)) = po;
      }
    }
    __syncthreads();
#pragma unroll
    for (int lt = 0; lt < 4; ++lt) {
      int rl = lt * 16 + fr;
      bf16x8 xa0 = *(const bf16x8*)(Xl + rl * 128 + (((0 + fg) ^ (rl & 7)) << 4));
      bf16x8 xa1 = *(const bf16x8*)(Xl + rl * 128 + (((4 + fg) ^ (rl & 7)) << 4));
#pragma unroll
      for (int pt = 0; pt < 4; ++pt) {
        f32x4 s = (f32x4){0.f, 0.f, 0.f, 0.f};
        s = MFMA16(xa0, ef[pt][0], s);
        s = MFMA16(xa1, ef[pt][1], s);
        uint2 pk2;
        pk2.x = f2bf2(fmaxf(s[0] * kScaling, 0.f), fmaxf(s[1] * kScaling, 0.f));
        pk2.y = f2bf2(fmaxf(s[2] * kScaling, 0.f), fmaxf(s[3] * kScaling, 0.f));
        int p = wv * 64 + pt * 16 + fr;
        int lbase = lt * 16 + fg * 4;
        int slot = lbase >> 3;
        *(uint2*)(Pl + p * 128 + ((slot ^ (p & 7)) << 4) + ((lbase & 7) << 1)) = pk2;
      }
    }
    asm volatile("s_waitcnt lgkmcnt(0)" ::: "memory");
    __builtin_amdgcn_sched_barrier(0);
#pragma unroll
    for (int kc = 0; kc < 2; ++kc) {
      bf16x8 pa[4], xb[4];
#pragma unroll
      for (int pt = 0; pt < 4; ++pt) {
        int p = wv * 64 + pt * 16 + fr;
        pa[pt] = *(const bf16x8*)(Pl + p * 128 + (((kc * 4 + fg) ^ (p & 7)) << 4));
      }
#pragma unroll
      for (int dt = 0; dt < 4; ++dt) {
        int dd = dt * 16 + fr;
        xb[dt] = *(const bf16x8*)(Xtl + dd * 128 +
                  ((((kc * 4 + fg) ^ (dd & 7) ^ (dd >> 3)) & 7) << 4));
      }
#pragma unroll
      for (int pt = 0; pt < 4; ++pt)
#pragma unroll
        for (int dt = 0; dt < 4; ++dt)
          acc[pt][dt] = MFMA16(pa[pt], xb[dt], acc[pt][dt]);
    }
  }
  unsigned short* op = parts + (size_t)(lc * 64 + bh) * PP * HDD;
#pragma unroll
  for (int pt = 0; pt < 4; ++pt)
#pragma unroll
    for (int dt = 0; dt < 4; ++dt)
#pragma unroll
      for (int r = 0; r < 4; ++r) {
        int p = wv * 64 + pt * 16 + fg * 4 + r;
        int dd = dt * 16 + fr;
        op[(size_t)p * HDD + dd] = f2bf(acc[pt][dt][r]);
      }
}

// Sum LC bf16 partials -> kv_raw bf16 as (P,B,D); vectorized x8, pk casts.
__global__ __launch_bounds__(256) void k_reduce(const unsigned short* __restrict__ parts,
                                                unsigned short* __restrict__ kv_raw_bf) {
  int u = blockIdx.x * 256 + threadIdx.x;     // 131072 units of 8 elems
  size_t off = (size_t)u * 8;
  float s[8] = {0.f, 0.f, 0.f, 0.f, 0.f, 0.f, 0.f, 0.f};
#pragma unroll
  for (int lcc = 0; lcc < LC; ++lcc) {
    bf16x8 v = *(const bf16x8*)(parts + (size_t)lcc * (64 * PP * HDD) + off);
#pragma unroll
    for (int j = 0; j < 8; ++j) s[j] += bf2f((unsigned short)v[j]);
  }
  int i = (int)off;
  int d = i & 63, p = (i >> 6) & 255, bh = i >> 14;
  int b = bh >> 4, h = bh & 15;
  uint4 o;
  o.x = f2bf2(s[0], s[1]); o.y = f2bf2(s[2], s[3]);
  o.z = f2bf2(s[4], s[5]); o.w = f2bf2(s[6], s[7]);
  *(uint4*)(kv_raw_bf + (size_t)(p * BB + b) * DD + h * HDD + d) = o;
}

// ---------------------------------------------------------------------------
// 128x128 GEMM body (small P=1024-row GEMMs).
// ---------------------------------------------------------------------------
template <int MODE, typename OUTT>
__device__ __forceinline__ void gemm_body(
    const unsigned short* __restrict__ A, const unsigned short* __restrict__ W,
    const float* __restrict__ bias, const float* __restrict__ ew,
    OUTT* __restrict__ C, int m0, int n0, char* Al, char* Bl) {
  const int tid = threadIdx.x;
  const int wv = tid >> 6, lane = tid & 63;
  const int fr = lane & 15, fg = lane >> 4;
  const int wr = wv >> 1, wc = wv & 1;

  f32x4 acc[4][4];
#pragma unroll
  for (int i = 0; i < 4; ++i)
#pragma unroll
    for (int j = 0; j < 4; ++j) acc[i][j] = (f32x4){0.f, 0.f, 0.f, 0.f};

  for (int k0 = 0; k0 < DD; k0 += 64) {
    __syncthreads();
#pragma unroll
    for (int j = 0; j < 4; ++j) {
      int u = tid + j * 256;
      int row = u >> 3, slot = u & 7;
      size_t gcol = (size_t)(k0 + 8 * (slot ^ (row & 7)));
      gll16(A + (size_t)(m0 + row) * DD + gcol, Al + u * 16);
      gll16(W + (size_t)(n0 + row) * DD + gcol, Bl + u * 16);
    }
    __syncthreads();
#pragma unroll
    for (int kc = 0; kc < 2; ++kc) {
      bf16x8 af[4], bfr[4];
#pragma unroll
      for (int mt = 0; mt < 4; ++mt) {
        int r = wr * 64 + mt * 16 + fr;
        af[mt] = *(const bf16x8*)(Al + r * 128 + (((kc * 4 + fg) ^ (r & 7)) << 4));
      }
#pragma unroll
      for (int nt = 0; nt < 4; ++nt) {
        int r = wc * 64 + nt * 16 + fr;
        bfr[nt] = *(const bf16x8*)(Bl + r * 128 + (((kc * 4 + fg) ^ (r & 7)) << 4));
      }
#pragma unroll
      for (int mt = 0; mt < 4; ++mt)
#pragma unroll
        for (int nt = 0; nt < 4; ++nt)
          acc[mt][nt] = MFMA16(af[mt], bfr[nt], acc[mt][nt]);
    }
  }

  float bs[4];
#pragma unroll
  for (int nt = 0; nt < 4; ++nt) bs[nt] = bias[n0 + wc * 64 + nt * 16 + fr];
#pragma unroll
  for (int mt = 0; mt < 4; ++mt)
#pragma unroll
    for (int nt = 0; nt < 4; ++nt) {
      int n = n0 + wc * 64 + nt * 16 + fr;
#pragma unroll
      for (int r = 0; r < 4; ++r) {
        int m = m0 + wr * 64 + mt * 16 + fg * 4 + r;
        float v = acc[mt][nt][r] + bs[nt];
        if (MODE == 1) v *= kScaling;
        if (MODE == 2) {
          int p = m >> 2, hh = n >> 6, d2 = n & 63;
          v += ew[(size_t)((hh << 8) + p) * HDD + d2];
        }
        if constexpr (sizeof(OUTT) == 2)
          C[(size_t)m * DD + n] = (OUTT)f2bf(v);
        else
          C[(size_t)m * DD + n] = v;
      }
    }
}

template <int MODE, typename OUTT>
__global__ __launch_bounds__(256) void k_gemm_mfma(
    const unsigned short* __restrict__ A, const unsigned short* __restrict__ W,
    const float* __restrict__ bias, const float* __restrict__ ew,
    OUTT* __restrict__ C) {
  __shared__ __align__(16) char Al[16384];
  __shared__ __align__(16) char Bl[16384];
  gemm_body<MODE, OUTT>(A, W, bias, ew, C, blockIdx.x * 128, blockIdx.y * 128, Al, Bl);
}

// K and V projections in one launch (blockIdx.z selects).
__global__ __launch_bounds__(256) void k_gemm_kv(
    const unsigned short* __restrict__ A,
    const unsigned short* __restrict__ Wk, const unsigned short* __restrict__ Wv,
    const float* __restrict__ kb, const float* __restrict__ vb,
    unsigned short* __restrict__ Ck, unsigned short* __restrict__ Cv) {
  __shared__ __align__(16) char Al[16384];
  __shared__ __align__(16) char Bl[16384];
  if (blockIdx.z == 0)
    gemm_body<0, unsigned short>(A, Wk, kb, nullptr, Ck,
                                 blockIdx.x * 128, blockIdx.y * 128, Al, Bl);
  else
    gemm_body<0, unsigned short>(A, Wv, vb, nullptr, Cv,
                                 blockIdx.x * 128, blockIdx.y * 128, Al, Bl);
}

// ---------------------------------------------------------------------------
// 256x256 GEMM, minimal-barrier schedule (unchanged).
// ---------------------------------------------------------------------------
template <int MODE, typename OUTT>
__global__ __launch_bounds__(512, 2) void k_gemm256(
    const unsigned short* __restrict__ A, const unsigned short* __restrict__ W,
    const float* __restrict__ bias, OUTT* __restrict__ C) {
  __shared__ __align__(16) char lds[131072];
  const int tid = threadIdx.x;
  const int wv = tid >> 6, lane = tid & 63;
  const int fr = lane & 15, fg = lane >> 4;
  const int wm = wv >> 2, wn = wv & 3;
  const int m0 = blockIdx.x * 256, n0 = blockIdx.y * 256;
  const int srow = tid >> 2, sslot = tid & 3;

  auto stageHalf = [&](const unsigned short* __restrict__ G, int g0, int colbase,
                       int dstBase) {
#pragma unroll
    for (int j = 0; j < 2; ++j) {
      int row = srow + j * 128;
      int gs = sslot ^ ((row >> 1) & 3);
      gll16(G + (size_t)(g0 + row) * DD + colbase + gs * 8,
            lds + dstBase + (tid + j * 512) * 16);
    }
  };
  auto rdA = [&](int mf, int kc, int cb) -> bf16x8 {
    int r = wm * 128 + mf * 16 + fr;
    return *(const bf16x8*)(lds + cb + kc * 16384 + r * 64 +
                            ((fg ^ ((r >> 1) & 3)) << 4));
  };
  auto rdB = [&](int nf, int kc, int cb) -> bf16x8 {
    int r = wn * 64 + nf * 16 + fr;
    return *(const bf16x8*)(lds + cb + 32768 + kc * 16384 + r * 64 +
                            ((fg ^ ((r >> 1) & 3)) << 4));
  };

  f32x4 acc[8][4];
#pragma unroll
  for (int i = 0; i < 8; ++i)
#pragma unroll
    for (int j = 0; j < 4; ++j) acc[i][j] = (f32x4){0.f, 0.f, 0.f, 0.f};
  bf16x8 a[8], b[4];

  stageHalf(A, m0, 0, 0);
  stageHalf(W, n0, 0, 32768);
  stageHalf(A, m0, 32, 16384);
  stageHalf(W, n0, 32, 32768 + 16384);
  stageHalf(A, m0, 64, 65536);
  stageHalf(W, n0, 64, 65536 + 32768);
  asm volatile("s_waitcnt vmcnt(4)" ::: "memory");   // tile0 arrived
  __builtin_amdgcn_s_barrier();

  const int NT = DD / 64;   // 16
  for (int t = 0; t < NT; ++t) {
    const int cb = (t & 1) << 16;
    const int nb = cb ^ 65536;
    const int k1 = (t + 1) * 64, k2 = (t + 2) * 64;

    // ---- half 1: kc0 (all mf), stage t+1.kc1 into nb
#pragma unroll
    for (int i = 0; i < 8; ++i) a[i] = rdA(i, 0, cb);
#pragma unroll
    for (int i = 0; i < 4; ++i) b[i] = rdB(i, 0, cb);
    if (t + 1 < NT) {
      stageHalf(A, m0, k1 + 32, nb + 16384);
      stageHalf(W, n0, k1 + 32, nb + 32768 + 16384);
    }
    asm volatile("s_waitcnt lgkmcnt(0)" ::: "memory");
    __builtin_amdgcn_sched_barrier(0);
    __builtin_amdgcn_s_setprio(1);
#pragma unroll
    for (int mf = 0; mf < 8; ++mf)
#pragma unroll
      for (int nf = 0; nf < 4; ++nf)
        acc[mf][nf] = MFMA16(a[mf], b[nf], acc[mf][nf]);
    __builtin_amdgcn_s_setprio(0);
    __builtin_amdgcn_s_barrier();   // mid: kc0 reads done across waves

    // ---- half 2: kc1 (all mf), stage t+2.kc0 into cb
#pragma unroll
    for (int i = 0; i < 8; ++i) a[i] = rdA(i, 1, cb);
#pragma unroll
    for (int i = 0; i < 4; ++i) b[i] = rdB(i, 1, cb);
    if (t + 2 < NT) {
      stageHalf(A, m0, k2, cb);
      stageHalf(W, n0, k2, cb + 32768);
    }
    asm volatile("s_waitcnt lgkmcnt(0)" ::: "memory");
    __builtin_amdgcn_sched_barrier(0);
    __builtin_amdgcn_s_setprio(1);
#pragma unroll
    for (int mf = 0; mf < 8; ++mf)
#pragma unroll
      for (int nf = 0; nf < 4; ++nf)
        acc[mf][nf] = MFMA16(a[mf], b[nf], acc[mf][nf]);
    __builtin_amdgcn_s_setprio(0);
    if (t + 2 < NT) {
      asm volatile("s_waitcnt vmcnt(4)" ::: "memory");   // t+1 fully arrived
    } else if (t + 1 < NT) {
      asm volatile("s_waitcnt vmcnt(0)" ::: "memory");   // drain for last tile
    }
    __builtin_amdgcn_s_barrier();   // end of tile
  }

  float bs[4];
#pragma unroll
  for (int nf = 0; nf < 4; ++nf) bs[nf] = bias[n0 + wn * 64 + nf * 16 + fr];
#pragma unroll
  for (int mf = 0; mf < 8; ++mf)
#pragma unroll
    for (int nf = 0; nf < 4; ++nf) {
      int n = n0 + wn * 64 + nf * 16 + fr;
#pragma unroll
      for (int r = 0; r < 4; ++r) {
        int m = m0 + wm * 128 + mf * 16 + fg * 4 + r;
        float v = acc[mf][nf][r] + bs[nf];
        if (MODE == 1) v *= kScaling;
        if constexpr (sizeof(OUTT) == 2)
          C[(size_t)m * DD + n] = (OUTT)f2bf(v);
        else
          C[(size_t)m * DD + n] = v;
      }
    }
}

// LayerNorm over D=1024; fp32 in -> bf16 out. One block per row.
__global__ __launch_bounds__(256) void k_ln(const float* __restrict__ x,
                                            const float* __restrict__ g,
                                            const float* __restrict__ bb,
                                            unsigned short* __restrict__ y) {
  const int r = blockIdx.x;
  const int tid = threadIdx.x;
  const float* xr = x + (size_t)r * DD;
  float4 v = *(const float4*)(xr + tid * 4);
  float s1 = v.x + v.y + v.z + v.w;
  float s2 = v.x * v.x + v.y * v.y + v.z * v.z + v.w * v.w;
#pragma unroll
  for (int off = 32; off > 0; off >>= 1) {
    s1 += __shfl_down(s1, off);
    s2 += __shfl_down(s2, off);
  }
  __shared__ float w1[4], w2[4];
  if ((tid & 63) == 0) { w1[tid >> 6] = s1; w2[tid >> 6] = s2; }
  __syncthreads();
  float S1 = w1[0] + w1[1] + w1[2] + w1[3];
  float S2 = w2[0] + w2[1] + w2[2] + w2[3];
  float mean = S1 * (1.f / DD);
  float var = S2 * (1.f / DD) - mean * mean;
  float rstd = rsqrtf(var + kEps);
  float4 gv = *(const float4*)(g + tid * 4);
  float4 bv = *(const float4*)(bb + tid * 4);
  uint2 o;
  o.x = f2bf2((v.x - mean) * rstd * gv.x + bv.x, (v.y - mean) * rstd * gv.y + bv.y);
  o.y = f2bf2((v.z - mean) * rstd * gv.z + bv.z, (v.w - mean) * rstd * gv.w + bv.w);
  *(uint2*)(y + (size_t)r * DD + tid * 4) = o;
}

// ---------------------------------------------------------------------------
// Attention: QBLK=128; V reg-prefetch w/ counted vmcnt; pk casts for P.
// ---------------------------------------------------------------------------
__global__ __launch_bounds__(512, 2) void k_attn_mfma(
    const unsigned short* __restrict__ qbf, const unsigned short* __restrict__ kbf,
    const unsigned short* __restrict__ vbf, unsigned short* __restrict__ attn) {
  const int bh = blockIdx.y;
  const int b = bh >> 4, h = bh & 15;
  const int tid = threadIdx.x, wv = tid >> 6, lane = tid & 63;
  const int fr = lane & 15, fg = lane >> 4;
  const int bl0 = blockIdx.x * 128;

  __shared__ __align__(16) char Kl[16384];    // [128p][64d] swz rows of 128B
  __shared__ __align__(16) char Vt[16384];    // 2 chunks of [64 dd][64 p]
  __shared__ __align__(16) char Pl[32768];    // 8 waves x [16 l][128 p]

  const size_t qrow = ((size_t)(bl0 + wv * 16 + fr) * BB + b) * DD + h * HDD;
  bf16x8 qf0 = *(const bf16x8*)(qbf + qrow + fg * 8);
  bf16x8 qf1 = *(const bf16x8*)(qbf + qrow + 32 + fg * 8);

  f32x4 o[4];
#pragma unroll
  for (int dt = 0; dt < 4; ++dt) o[dt] = (f32x4){0.f, 0.f, 0.f, 0.f};
  float psum = 0.f;
  char* Pw = Pl + wv * 4096;

  const int p2 = tid >> 3, c8v = tid & 7;
  const size_t vbase = ((size_t)((2 * p2) * BB + b)) * DD + h * HDD + c8v * 8;
  // prologue: ph0 V loads -> regs
  bf16x8 va = *(const bf16x8*)(vbf + vbase);
  bf16x8 vb_ = *(const bf16x8*)(vbf + vbase + BB * DD);

#pragma unroll
  for (int ph = 0; ph < 2; ++ph) {
    if (ph == 1) {
      asm volatile("s_waitcnt lgkmcnt(0)" ::: "memory");
      __builtin_amdgcn_s_barrier();
    }
    // K gll16 first (so counted vmcnt below targets exactly these)
#pragma unroll
    for (int j = 0; j < 2; ++j) {
      int u = tid + j * 512;
      int p = u >> 3, slot = u & 7;
      gll16(kbf + ((size_t)((ph * 128 + p) * BB + b)) * DD + h * HDD +
                8 * (slot ^ (p & 7)),
            Kl + u * 16);
    }
    // V LDS writes from regs
    {
      int pl = (2 * p2) & 63, pc = p2 >> 5;
      char* base = Vt + pc * 8192;
#pragma unroll
      for (int i = 0; i < 8; ++i) {
        int dd = c8v * 8 + i;
        unsigned int packed = (unsigned int)(unsigned short)va[i] |
                              ((unsigned int)(unsigned short)vb_[i] << 16);
        *(unsigned int*)(base + dd * 128 +
            ((((pl >> 3) ^ (dd & 7) ^ (dd >> 3)) & 7) << 4) + ((pl & 7) << 1)) = packed;
      }
    }
    bf16x8 van, vbn;
    if (ph == 0) {   // prefetch ph1 V (rows +128)
      van = *(const bf16x8*)(vbf + vbase + (size_t)128 * BB * DD);
      vbn = *(const bf16x8*)(vbf + vbase + (size_t)129 * BB * DD);
    }
    asm volatile("s_waitcnt lgkmcnt(0)" ::: "memory");
    if (ph == 0) {
      asm volatile("s_waitcnt vmcnt(2)" ::: "memory");   // K done, V-prefetch flying
    } else {
      asm volatile("s_waitcnt vmcnt(0)" ::: "memory");
    }
    __builtin_amdgcn_s_barrier();
    __builtin_amdgcn_sched_barrier(0);

    f32x4 s[8];
    __builtin_amdgcn_s_setprio(1);
#pragma unroll
    for (int pt = 0; pt < 8; ++pt) {
      int pr = pt * 16 + fr;
      bf16x8 a0 = *(const bf16x8*)(Kl + pr * 128 + ((fg ^ (pr & 7)) << 4));
      bf16x8 a1 = *(const bf16x8*)(Kl + pr * 128 + (((4 + fg) ^ (pr & 7)) << 4));
      f32x4 acc = (f32x4){0.f, 0.f, 0.f, 0.f};
      acc = MFMA16(a0, qf0, acc);
      acc = MFMA16(a1, qf1, acc);
      s[pt] = acc;
    }
    __builtin_amdgcn_s_setprio(0);

#pragma unroll
    for (int pt = 0; pt < 8; ++pt) {
      float e0 = __expf(s[pt][0]), e1 = __expf(s[pt][1]);
      float e2 = __expf(s[pt][2]), e3 = __expf(s[pt][3]);
      psum += (e0 + e1) + (e2 + e3);
      uint2 pk2;
      pk2.x = f2bf2(e0, e1);
      pk2.y = f2bf2(e2, e3);
      int pbyte = (pt * 16 + fg * 4) * 2;
      int slot = pbyte >> 4, rem = pbyte & 15;
      *(uint2*)(Pw + fr * 256 + ((slot ^ (fr & 7)) << 4) + rem) = pk2;
    }
    asm volatile("s_waitcnt lgkmcnt(0)" ::: "memory");
    __builtin_amdgcn_sched_barrier(0);

    __builtin_amdgcn_s_setprio(1);
#pragma unroll
    for (int kc = 0; kc < 4; ++kc) {
      int slot = kc * 4 + fg;
      bf16x8 pa = *(const bf16x8*)(Pw + fr * 256 + ((slot ^ (fr & 7)) << 4));
      int sl2 = (kc & 1) * 4 + fg;
#pragma unroll
      for (int dt = 0; dt < 4; ++dt) {
        int dd = dt * 16 + fr;
        bf16x8 vbr = *(const bf16x8*)(Vt + (kc >> 1) * 8192 + dd * 128 +
                     (((sl2 ^ (dd & 7) ^ (dd >> 3)) & 7) << 4));
        o[dt] = MFMA16(pa, vbr, o[dt]);
      }
    }
    __builtin_amdgcn_s_setprio(0);

    if (ph == 0) { va = van; vb_ = vbn; }
  }

  psum += __shfl_xor(psum, 16);
  psum += __shfl_xor(psum, 32);

#pragma unroll
  for (int r = 0; r < 4; ++r) {
    int lloc = fg * 4 + r;
    float inv = 1.f / __shfl(psum, lloc);
    unsigned short* op = attn +
        ((size_t)(bl0 + wv * 16 + lloc) * BB + b) * DD + h * HDD;
#pragma unroll
    for (int dt = 0; dt < 4; ++dt)
      op[dt * 16 + fr] = f2bf(o[dt][r] * inv);
  }
}

extern "C" void kernel_launch(void* const* d_in, const int* in_sizes, int n_in,
                              void* d_out, int out_size, void* d_ws, size_t ws_size,
                              hipStream_t stream) {
  const float* query   = (const float*)d_in[0];
  const float* q_w     = (const float*)d_in[1];
  const float* q_b     = (const float*)d_in[2];
  const float* k_w     = (const float*)d_in[3];
  const float* k_b     = (const float*)d_in[4];
  const float* v_w     = (const float*)d_in[5];
  const float* v_b     = (const float*)d_in[6];
  const float* e_weight= (const float*)d_in[7];
  const float* e_out_w = (const float*)d_in[8];
  const float* e_out_b = (const float*)d_in[9];
  const float* ln_g    = (const float*)d_in[10];
  const float* ln_b    = (const float*)d_in[11];
  const float* out_w   = (const float*)d_in[12];
  const float* out_b   = (const float*)d_in[13];
  float* out = (float*)d_out;

  char* w = (char*)d_ws;
  unsigned short* parts   = (unsigned short*)w;                 // 16 MB, dead after reduce
  unsigned short* q_bf    = (unsigned short*)w;                 // 32 MB (alias, after reduce)
  unsigned short* attn_bf = (unsigned short*)(w + (32u << 20)); // 32 MB
  unsigned short* query_bf= (unsigned short*)(w + (64u << 20)); // 32 MB
  unsigned short* kv_raw  = (unsigned short*)(w + (96u << 20)); // 2 MB
  float* kv_eo            = (float*)(w + (98u << 20));          // 4 MB
  unsigned short* kv_ln   = (unsigned short*)(w + (102u << 20));// 2 MB
  unsigned short* k_buf   = (unsigned short*)(w + (104u << 20));// 2 MB
  unsigned short* v_buf   = (unsigned short*)(w + (106u << 20));// 2 MB
  unsigned short* wq  = (unsigned short*)(w + (108u << 20));
  unsigned short* wk  = (unsigned short*)(w + (110u << 20));
  unsigned short* wv_ = (unsigned short*)(w + (112u << 20));
  unsigned short* weo = (unsigned short*)(w + (114u << 20));
  unsigned short* wo  = (unsigned short*)(w + (116u << 20));
  unsigned short* ewb = (unsigned short*)(w + (118u << 20));    // 0.5 MB

  k_cvt_w<<<2688, 256, 0, stream>>>(q_w, k_w, v_w, e_out_w, out_w, e_weight,
                                    wq, wk, wv_, weo, wo, ewb);

  k_compress_mfma<<<dim3(64, LC), 256, 0, stream>>>(query, ewb, query_bf, parts);
  k_reduce<<<512, 256, 0, stream>>>(parts, kv_raw);
  k_gemm_mfma<2, float><<<dim3(8, 8), 256, 0, stream>>>(kv_raw, weo, e_out_b, e_weight, kv_eo);
  k_ln<<<PP * BB, 256, 0, stream>>>(kv_eo, ln_g, ln_b, kv_ln);
  k_gemm256<1, unsigned short><<<dim3(64, 4), 512, 0, stream>>>(query_bf, wq, q_b, q_bf);
  k_gemm_kv<<<dim3(8, 8, 2), 256, 0, stream>>>(kv_ln, wk, wv_, k_b, v_b, k_buf, v_buf);
  k_attn_mfma<<<dim3(32, 64), 512, 0, stream>>>(q_bf, k_buf, v_buf, attn_bf);
  k_gemm256<0, float><<<dim3(64, 4), 512, 0, stream>>>(attn_bf, wo, out_b, out);
}

// Round 17
// 198.111 us; speedup vs baseline: 1.0864x; 1.0076x over previous
//
#include <hip/hip_runtime.h>
#include <hip/hip_bf16.h>
#include <cstdint>
#include <cstddef>

#define LL 4096
#define BB 4
#define DD 1024
#define HH 16
#define PP 256
#define HDD 64
#define LC 8
#define LCHUNK 512

constexpr float kScaling = 0.125f;   // HD^-0.5
constexpr float kEps = 1e-5f;

typedef __attribute__((ext_vector_type(8))) short bf16x8;   // 8 bf16 = 4 VGPR
typedef __attribute__((ext_vector_type(4))) short short4v;
typedef __attribute__((ext_vector_type(4))) float f32x4;

#define MFMA16(a, b, c) __builtin_amdgcn_mfma_f32_16x16x32_bf16((a), (b), (c), 0, 0, 0)

__device__ __forceinline__ unsigned short f2bf(float f) {
  unsigned int u = __builtin_bit_cast(unsigned int, f);
  u += 0x7FFFu + ((u >> 16) & 1u);           // round-to-nearest-even
  return (unsigned short)(u >> 16);
}
// paired RNE cast -> compiler emits v_cvt_pk_bf16_f32 (1 op / 2 elems)
__device__ __forceinline__ unsigned int f2bf2(float lo, float hi) {
  __hip_bfloat162 h = __float22bfloat162_rn(make_float2(lo, hi));
  unsigned int u;
  __builtin_memcpy(&u, &h, 4);
  return u;
}
__device__ __forceinline__ float bf2f(unsigned short u) {
  return __builtin_bit_cast(float, ((unsigned int)u) << 16);
}

__device__ __forceinline__ void gll16(const void* g, void* l) {
  __builtin_amdgcn_global_load_lds(
      (const __attribute__((address_space(1))) unsigned int*)g,
      (__attribute__((address_space(3))) unsigned int*)l, 16, 0, 0);
}

// ---------------------------------------------------------------------------
// Weights-only fp32 -> bf16 convert (pk casts).
// ---------------------------------------------------------------------------
__global__ __launch_bounds__(256) void k_cvt_w(
    const float* __restrict__ w0, const float* __restrict__ w1,
    const float* __restrict__ w2, const float* __restrict__ w3,
    const float* __restrict__ w4, const float* __restrict__ w5,
    unsigned short* __restrict__ d0, unsigned short* __restrict__ d1,
    unsigned short* __restrict__ d2, unsigned short* __restrict__ d3,
    unsigned short* __restrict__ d4, unsigned short* __restrict__ d5) {
  int i = blockIdx.x * 256 + threadIdx.x;
  int w = i >> 17, off = i & 131071;
  const float* src; unsigned short* dst;
  if (w == 0) { src = w0; dst = d0; }
  else if (w == 1) { src = w1; dst = d1; }
  else if (w == 2) { src = w2; dst = d2; }
  else if (w == 3) { src = w3; dst = d3; }
  else if (w == 4) { src = w4; dst = d4; }
  else { if (off >= 32768) return; src = w5; dst = d5; }
  const float4* s = (const float4*)(src + (size_t)off * 8);
  float4 a = s[0], b = s[1];
  uint4 o;
  o.x = f2bf2(a.x, a.y); o.y = f2bf2(a.z, a.w);
  o.z = f2bf2(b.x, b.y); o.w = f2bf2(b.z, b.w);
  *(uint4*)(dst + (size_t)off * 8) = o;
}

// ---------------------------------------------------------------------------
// Compress (MFMA) + inline query cvt. fp32 query now staged async into LDS
// (gll16, pre-swizzled source) one tile ahead; cvt reads LDS, not HBM.
// LDS 64KB: Xf 16K + Xl 8K + Xtl 8K + Pl 32K -> 2 blocks/CU (grid 512 = 2/CU).
// ---------------------------------------------------------------------------
__global__ __launch_bounds__(256) void k_compress_mfma(
    const float* __restrict__ q32, const unsigned short* __restrict__ ewbf,
    unsigned short* __restrict__ qbf_out, unsigned short* __restrict__ parts) {
  const int bh = blockIdx.x, lc = blockIdx.y;
  const int b = bh >> 4, h = bh & 15;
  const int tid = threadIdx.x, wv = tid >> 6, lane = tid & 63;
  const int fr = lane & 15, fg = lane >> 4;

  __shared__ __align__(16) char Xf[16384];   // fp32 [64 l][256B row, 32B-slot swz]
  __shared__ __align__(16) char Xl[8192];    // [l][d] bf16 rows of 128B
  __shared__ __align__(16) char Xtl[8192];   // [d][l]
  __shared__ __align__(16) char Pl[32768];   // [p][l] rows of 128B

  bf16x8 ef[4][2];
#pragma unroll
  for (int pt = 0; pt < 4; ++pt)
#pragma unroll
    for (int kc = 0; kc < 2; ++kc)
      ef[pt][kc] = *(const bf16x8*)(ewbf +
          (size_t)((h * PP + wv * 64 + pt * 16 + fr) * HDD) + kc * 32 + fg * 8);

  f32x4 acc[4][4];
#pragma unroll
  for (int i = 0; i < 4; ++i)
#pragma unroll
    for (int j = 0; j < 4; ++j) acc[i][j] = (f32x4){0.f, 0.f, 0.f, 0.f};

  const int l0 = lc * LCHUNK;

  // async stage of tile t's fp32 query into Xf. LDS linear (u*16); global
  // source pre-swizzled so slot s of row l holds float-cols 8*(s^((l>>1)&7)).
  auto stageX = [&](int t) {
#pragma unroll
    for (int j = 0; j < 4; ++j) {
      int u = tid + j * 256;
      int l = u >> 4, h16 = u & 15;
      int col = 8 * ((h16 >> 1) ^ ((l >> 1) & 7)) + (h16 & 1) * 4;
      gll16(q32 + ((size_t)(l0 + t * 64 + l) * BB + b) * DD + h * HDD + col,
            Xf + u * 16);
    }
  };

  stageX(0);
  __syncthreads();   // drains vmcnt: tile0 staged

  for (int t = 0; t < LCHUNK / 64; ++t) {
    // ---- cvt phase: Xf (LDS fp32) -> bf16 -> qbf_out + Xl + Xtl
    {
      int l2 = tid >> 3, c8 = tid & 7;
      int l = 2 * l2;
      int slot = ((c8 ^ (l2 & 7)) << 5);
      float4 a0 = *(const float4*)(Xf + l * 256 + slot);
      float4 a1 = *(const float4*)(Xf + l * 256 + slot + 16);
      float4 b0 = *(const float4*)(Xf + (l + 1) * 256 + slot);
      float4 b1 = *(const float4*)(Xf + (l + 1) * 256 + slot + 16);
      size_t rowbase = ((size_t)(l0 + t * 64 + l) * BB + b) * DD + h * HDD + c8 * 8;
      unsigned int W[4], U[4];
      W[0] = f2bf2(a0.x, a0.y); W[1] = f2bf2(a0.z, a0.w);
      W[2] = f2bf2(a1.x, a1.y); W[3] = f2bf2(a1.z, a1.w);
      U[0] = f2bf2(b0.x, b0.y); U[1] = f2bf2(b0.z, b0.w);
      U[2] = f2bf2(b1.x, b1.y); U[3] = f2bf2(b1.z, b1.w);
      uint4 V0 = {W[0], W[1], W[2], W[3]};
      uint4 V1 = {U[0], U[1], U[2], U[3]};
      *(uint4*)(qbf_out + rowbase) = V0;
      *(uint4*)(qbf_out + rowbase + BB * DD) = V1;
      *(uint4*)(Xl + l * 128 + ((c8 ^ (l & 7)) << 4)) = V0;
      *(uint4*)(Xl + (l + 1) * 128 + ((c8 ^ ((l + 1) & 7)) << 4)) = V1;
#pragma unroll
      for (int j = 0; j < 4; ++j) {
        int dd0 = c8 * 8 + 2 * j, dd1 = dd0 + 1;
        unsigned int pe = (W[j] & 0xFFFFu) | (U[j] << 16);
        unsigned int po = (W[j] >> 16) | (U[j] & 0xFFFF0000u);
        *(unsigned int*)(Xtl + dd0 * 128 +
            ((((l >> 3) ^ (dd0 & 7) ^ (dd0 >> 3)) & 7) << 4) + ((l & 7) << 1)) = pe;
        *(unsigned int*)(Xtl + dd1 * 128 +
            ((((l >> 3) ^ (dd1 & 7) ^ (dd1 >> 3)) & 7) << 4) + ((l & 7) << 1)) = po;
      }
    }
    __syncthreads();   // barrier A: Xl/Xtl visible; all waves done reading Xf
    if (t + 1 < LCHUNK / 64) stageX(t + 1);   // async; drains at barrier B

    // ---- MFMA phase
#pragma unroll
    for (int lt = 0; lt < 4; ++lt) {
      int rl = lt * 16 + fr;
      bf16x8 xa0 = *(const bf16x8*)(Xl + rl * 128 + (((0 + fg) ^ (rl & 7)) << 4));
      bf16x8 xa1 = *(const bf16x8*)(Xl + rl * 128 + (((4 + fg) ^ (rl & 7)) << 4));
#pragma unroll
      for (int pt = 0; pt < 4; ++pt) {
        f32x4 s = (f32x4){0.f, 0.f, 0.f, 0.f};
        s = MFMA16(xa0, ef[pt][0], s);
        s = MFMA16(xa1, ef[pt][1], s);
        uint2 pk2;
        pk2.x = f2bf2(fmaxf(s[0] * kScaling, 0.f), fmaxf(s[1] * kScaling, 0.f));
        pk2.y = f2bf2(fmaxf(s[2] * kScaling, 0.f), fmaxf(s[3] * kScaling, 0.f));
        int p = wv * 64 + pt * 16 + fr;
        int lbase = lt * 16 + fg * 4;
        int slot = lbase >> 3;
        *(uint2*)(Pl + p * 128 + ((slot ^ (p & 7)) << 4) + ((lbase & 7) << 1)) = pk2;
      }
    }
    asm volatile("s_waitcnt lgkmcnt(0)" ::: "memory");
    __builtin_amdgcn_sched_barrier(0);
#pragma unroll
    for (int kc = 0; kc < 2; ++kc) {
      bf16x8 pa[4], xb[4];
#pragma unroll
      for (int pt = 0; pt < 4; ++pt) {
        int p = wv * 64 + pt * 16 + fr;
        pa[pt] = *(const bf16x8*)(Pl + p * 128 + (((kc * 4 + fg) ^ (p & 7)) << 4));
      }
#pragma unroll
      for (int dt = 0; dt < 4; ++dt) {
        int dd = dt * 16 + fr;
        xb[dt] = *(const bf16x8*)(Xtl + dd * 128 +
                  ((((kc * 4 + fg) ^ (dd & 7) ^ (dd >> 3)) & 7) << 4));
      }
#pragma unroll
      for (int pt = 0; pt < 4; ++pt)
#pragma unroll
        for (int dt = 0; dt < 4; ++dt)
          acc[pt][dt] = MFMA16(pa[pt], xb[dt], acc[pt][dt]);
    }
    __syncthreads();   // barrier B: drains stage vmcnt; Xl/Xtl free
  }
  unsigned short* op = parts + (size_t)(lc * 64 + bh) * PP * HDD;
#pragma unroll
  for (int pt = 0; pt < 4; ++pt)
#pragma unroll
    for (int dt = 0; dt < 4; ++dt)
#pragma unroll
      for (int r = 0; r < 4; ++r) {
        int p = wv * 64 + pt * 16 + fg * 4 + r;
        int dd = dt * 16 + fr;
        op[(size_t)p * HDD + dd] = f2bf(acc[pt][dt][r]);
      }
}

// Sum LC bf16 partials -> kv_raw bf16 as (P,B,D); vectorized x8, pk casts.
__global__ __launch_bounds__(256) void k_reduce(const unsigned short* __restrict__ parts,
                                                unsigned short* __restrict__ kv_raw_bf) {
  int u = blockIdx.x * 256 + threadIdx.x;     // 131072 units of 8 elems
  size_t off = (size_t)u * 8;
  float s[8] = {0.f, 0.f, 0.f, 0.f, 0.f, 0.f, 0.f, 0.f};
#pragma unroll
  for (int lcc = 0; lcc < LC; ++lcc) {
    bf16x8 v = *(const bf16x8*)(parts + (size_t)lcc * (64 * PP * HDD) + off);
#pragma unroll
    for (int j = 0; j < 8; ++j) s[j] += bf2f((unsigned short)v[j]);
  }
  int i = (int)off;
  int d = i & 63, p = (i >> 6) & 255, bh = i >> 14;
  int b = bh >> 4, h = bh & 15;
  uint4 o;
  o.x = f2bf2(s[0], s[1]); o.y = f2bf2(s[2], s[3]);
  o.z = f2bf2(s[4], s[5]); o.w = f2bf2(s[6], s[7]);
  *(uint4*)(kv_raw_bf + (size_t)(p * BB + b) * DD + h * HDD + d) = o;
}

// ---------------------------------------------------------------------------
// 128x128 GEMM body (small P=1024-row GEMMs).
// ---------------------------------------------------------------------------
template <int MODE, typename OUTT>
__device__ __forceinline__ void gemm_body(
    const unsigned short* __restrict__ A, const unsigned short* __restrict__ W,
    const float* __restrict__ bias, const float* __restrict__ ew,
    OUTT* __restrict__ C, int m0, int n0, char* Al, char* Bl) {
  const int tid = threadIdx.x;
  const int wv = tid >> 6, lane = tid & 63;
  const int fr = lane & 15, fg = lane >> 4;
  const int wr = wv >> 1, wc = wv & 1;

  f32x4 acc[4][4];
#pragma unroll
  for (int i = 0; i < 4; ++i)
#pragma unroll
    for (int j = 0; j < 4; ++j) acc[i][j] = (f32x4){0.f, 0.f, 0.f, 0.f};

  for (int k0 = 0; k0 < DD; k0 += 64) {
    __syncthreads();
#pragma unroll
    for (int j = 0; j < 4; ++j) {
      int u = tid + j * 256;
      int row = u >> 3, slot = u & 7;
      size_t gcol = (size_t)(k0 + 8 * (slot ^ (row & 7)));
      gll16(A + (size_t)(m0 + row) * DD + gcol, Al + u * 16);
      gll16(W + (size_t)(n0 + row) * DD + gcol, Bl + u * 16);
    }
    __syncthreads();
#pragma unroll
    for (int kc = 0; kc < 2; ++kc) {
      bf16x8 af[4], bfr[4];
#pragma unroll
      for (int mt = 0; mt < 4; ++mt) {
        int r = wr * 64 + mt * 16 + fr;
        af[mt] = *(const bf16x8*)(Al + r * 128 + (((kc * 4 + fg) ^ (r & 7)) << 4));
      }
#pragma unroll
      for (int nt = 0; nt < 4; ++nt) {
        int r = wc * 64 + nt * 16 + fr;
        bfr[nt] = *(const bf16x8*)(Bl + r * 128 + (((kc * 4 + fg) ^ (r & 7)) << 4));
      }
#pragma unroll
      for (int mt = 0; mt < 4; ++mt)
#pragma unroll
        for (int nt = 0; nt < 4; ++nt)
          acc[mt][nt] = MFMA16(af[mt], bfr[nt], acc[mt][nt]);
    }
  }

  float bs[4];
#pragma unroll
  for (int nt = 0; nt < 4; ++nt) bs[nt] = bias[n0 + wc * 64 + nt * 16 + fr];
#pragma unroll
  for (int mt = 0; mt < 4; ++mt)
#pragma unroll
    for (int nt = 0; nt < 4; ++nt) {
      int n = n0 + wc * 64 + nt * 16 + fr;
#pragma unroll
      for (int r = 0; r < 4; ++r) {
        int m = m0 + wr * 64 + mt * 16 + fg * 4 + r;
        float v = acc[mt][nt][r] + bs[nt];
        if (MODE == 1) v *= kScaling;
        if (MODE == 2) {
          int p = m >> 2, hh = n >> 6, d2 = n & 63;
          v += ew[(size_t)((hh << 8) + p) * HDD + d2];
        }
        if constexpr (sizeof(OUTT) == 2)
          C[(size_t)m * DD + n] = (OUTT)f2bf(v);
        else
          C[(size_t)m * DD + n] = v;
      }
    }
}

template <int MODE, typename OUTT>
__global__ __launch_bounds__(256) void k_gemm_mfma(
    const unsigned short* __restrict__ A, const unsigned short* __restrict__ W,
    const float* __restrict__ bias, const float* __restrict__ ew,
    OUTT* __restrict__ C) {
  __shared__ __align__(16) char Al[16384];
  __shared__ __align__(16) char Bl[16384];
  gemm_body<MODE, OUTT>(A, W, bias, ew, C, blockIdx.x * 128, blockIdx.y * 128, Al, Bl);
}

// K and V projections in one launch (blockIdx.z selects).
__global__ __launch_bounds__(256) void k_gemm_kv(
    const unsigned short* __restrict__ A,
    const unsigned short* __restrict__ Wk, const unsigned short* __restrict__ Wv,
    const float* __restrict__ kb, const float* __restrict__ vb,
    unsigned short* __restrict__ Ck, unsigned short* __restrict__ Cv) {
  __shared__ __align__(16) char Al[16384];
  __shared__ __align__(16) char Bl[16384];
  if (blockIdx.z == 0)
    gemm_body<0, unsigned short>(A, Wk, kb, nullptr, Ck,
                                 blockIdx.x * 128, blockIdx.y * 128, Al, Bl);
  else
    gemm_body<0, unsigned short>(A, Wv, vb, nullptr, Cv,
                                 blockIdx.x * 128, blockIdx.y * 128, Al, Bl);
}

// ---------------------------------------------------------------------------
// 256x256 GEMM, minimal-barrier schedule (unchanged).
// ---------------------------------------------------------------------------
template <int MODE, typename OUTT>
__global__ __launch_bounds__(512, 2) void k_gemm256(
    const unsigned short* __restrict__ A, const unsigned short* __restrict__ W,
    const float* __restrict__ bias, OUTT* __restrict__ C) {
  __shared__ __align__(16) char lds[131072];
  const int tid = threadIdx.x;
  const int wv = tid >> 6, lane = tid & 63;
  const int fr = lane & 15, fg = lane >> 4;
  const int wm = wv >> 2, wn = wv & 3;
  const int m0 = blockIdx.x * 256, n0 = blockIdx.y * 256;
  const int srow = tid >> 2, sslot = tid & 3;

  auto stageHalf = [&](const unsigned short* __restrict__ G, int g0, int colbase,
                       int dstBase) {
#pragma unroll
    for (int j = 0; j < 2; ++j) {
      int row = srow + j * 128;
      int gs = sslot ^ ((row >> 1) & 3);
      gll16(G + (size_t)(g0 + row) * DD + colbase + gs * 8,
            lds + dstBase + (tid + j * 512) * 16);
    }
  };
  auto rdA = [&](int mf, int kc, int cb) -> bf16x8 {
    int r = wm * 128 + mf * 16 + fr;
    return *(const bf16x8*)(lds + cb + kc * 16384 + r * 64 +
                            ((fg ^ ((r >> 1) & 3)) << 4));
  };
  auto rdB = [&](int nf, int kc, int cb) -> bf16x8 {
    int r = wn * 64 + nf * 16 + fr;
    return *(const bf16x8*)(lds + cb + 32768 + kc * 16384 + r * 64 +
                            ((fg ^ ((r >> 1) & 3)) << 4));
  };

  f32x4 acc[8][4];
#pragma unroll
  for (int i = 0; i < 8; ++i)
#pragma unroll
    for (int j = 0; j < 4; ++j) acc[i][j] = (f32x4){0.f, 0.f, 0.f, 0.f};
  bf16x8 a[8], b[4];

  stageHalf(A, m0, 0, 0);
  stageHalf(W, n0, 0, 32768);
  stageHalf(A, m0, 32, 16384);
  stageHalf(W, n0, 32, 32768 + 16384);
  stageHalf(A, m0, 64, 65536);
  stageHalf(W, n0, 64, 65536 + 32768);
  asm volatile("s_waitcnt vmcnt(4)" ::: "memory");   // tile0 arrived
  __builtin_amdgcn_s_barrier();

  const int NT = DD / 64;   // 16
  for (int t = 0; t < NT; ++t) {
    const int cb = (t & 1) << 16;
    const int nb = cb ^ 65536;
    const int k1 = (t + 1) * 64, k2 = (t + 2) * 64;

    // ---- half 1: kc0 (all mf), stage t+1.kc1 into nb
#pragma unroll
    for (int i = 0; i < 8; ++i) a[i] = rdA(i, 0, cb);
#pragma unroll
    for (int i = 0; i < 4; ++i) b[i] = rdB(i, 0, cb);
    if (t + 1 < NT) {
      stageHalf(A, m0, k1 + 32, nb + 16384);
      stageHalf(W, n0, k1 + 32, nb + 32768 + 16384);
    }
    asm volatile("s_waitcnt lgkmcnt(0)" ::: "memory");
    __builtin_amdgcn_sched_barrier(0);
    __builtin_amdgcn_s_setprio(1);
#pragma unroll
    for (int mf = 0; mf < 8; ++mf)
#pragma unroll
      for (int nf = 0; nf < 4; ++nf)
        acc[mf][nf] = MFMA16(a[mf], b[nf], acc[mf][nf]);
    __builtin_amdgcn_s_setprio(0);
    __builtin_amdgcn_s_barrier();   // mid: kc0 reads done across waves

    // ---- half 2: kc1 (all mf), stage t+2.kc0 into cb
#pragma unroll
    for (int i = 0; i < 8; ++i) a[i] = rdA(i, 1, cb);
#pragma unroll
    for (int i = 0; i < 4; ++i) b[i] = rdB(i, 1, cb);
    if (t + 2 < NT) {
      stageHalf(A, m0, k2, cb);
      stageHalf(W, n0, k2, cb + 32768);
    }
    asm volatile("s_waitcnt lgkmcnt(0)" ::: "memory");
    __builtin_amdgcn_sched_barrier(0);
    __builtin_amdgcn_s_setprio(1);
#pragma unroll
    for (int mf = 0; mf < 8; ++mf)
#pragma unroll
      for (int nf = 0; nf < 4; ++nf)
        acc[mf][nf] = MFMA16(a[mf], b[nf], acc[mf][nf]);
    __builtin_amdgcn_s_setprio(0);
    if (t + 2 < NT) {
      asm volatile("s_waitcnt vmcnt(4)" ::: "memory");   // t+1 fully arrived
    } else if (t + 1 < NT) {
      asm volatile("s_waitcnt vmcnt(0)" ::: "memory");   // drain for last tile
    }
    __builtin_amdgcn_s_barrier();   // end of tile
  }

  float bs[4];
#pragma unroll
  for (int nf = 0; nf < 4; ++nf) bs[nf] = bias[n0 + wn * 64 + nf * 16 + fr];
#pragma unroll
  for (int mf = 0; mf < 8; ++mf)
#pragma unroll
    for (int nf = 0; nf < 4; ++nf) {
      int n = n0 + wn * 64 + nf * 16 + fr;
#pragma unroll
      for (int r = 0; r < 4; ++r) {
        int m = m0 + wm * 128 + mf * 16 + fg * 4 + r;
        float v = acc[mf][nf][r] + bs[nf];
        if (MODE == 1) v *= kScaling;
        if constexpr (sizeof(OUTT) == 2)
          C[(size_t)m * DD + n] = (OUTT)f2bf(v);
        else
          C[(size_t)m * DD + n] = v;
      }
    }
}

// LayerNorm over D=1024; fp32 in -> bf16 out. One block per row.
__global__ __launch_bounds__(256) void k_ln(const float* __restrict__ x,
                                            const float* __restrict__ g,
                                            const float* __restrict__ bb,
                                            unsigned short* __restrict__ y) {
  const int r = blockIdx.x;
  const int tid = threadIdx.x;
  const float* xr = x + (size_t)r * DD;
  float4 v = *(const float4*)(xr + tid * 4);
  float s1 = v.x + v.y + v.z + v.w;
  float s2 = v.x * v.x + v.y * v.y + v.z * v.z + v.w * v.w;
#pragma unroll
  for (int off = 32; off > 0; off >>= 1) {
    s1 += __shfl_down(s1, off);
    s2 += __shfl_down(s2, off);
  }
  __shared__ float w1[4], w2[4];
  if ((tid & 63) == 0) { w1[tid >> 6] = s1; w2[tid >> 6] = s2; }
  __syncthreads();
  float S1 = w1[0] + w1[1] + w1[2] + w1[3];
  float S2 = w2[0] + w2[1] + w2[2] + w2[3];
  float mean = S1 * (1.f / DD);
  float var = S2 * (1.f / DD) - mean * mean;
  float rstd = rsqrtf(var + kEps);
  float4 gv = *(const float4*)(g + tid * 4);
  float4 bv = *(const float4*)(bb + tid * 4);
  uint2 o;
  o.x = f2bf2((v.x - mean) * rstd * gv.x + bv.x, (v.y - mean) * rstd * gv.y + bv.y);
  o.y = f2bf2((v.z - mean) * rstd * gv.z + bv.z, (v.w - mean) * rstd * gv.w + bv.w);
  *(uint2*)(y + (size_t)r * DD + tid * 4) = o;
}

// ---------------------------------------------------------------------------
// Attention: QBLK=128; V reg-prefetch w/ counted vmcnt; pk casts for P.
// ---------------------------------------------------------------------------
__global__ __launch_bounds__(512, 2) void k_attn_mfma(
    const unsigned short* __restrict__ qbf, const unsigned short* __restrict__ kbf,
    const unsigned short* __restrict__ vbf, unsigned short* __restrict__ attn) {
  const int bh = blockIdx.y;
  const int b = bh >> 4, h = bh & 15;
  const int tid = threadIdx.x, wv = tid >> 6, lane = tid & 63;
  const int fr = lane & 15, fg = lane >> 4;
  const int bl0 = blockIdx.x * 128;

  __shared__ __align__(16) char Kl[16384];    // [128p][64d] swz rows of 128B
  __shared__ __align__(16) char Vt[16384];    // 2 chunks of [64 dd][64 p]
  __shared__ __align__(16) char Pl[32768];    // 8 waves x [16 l][128 p]

  const size_t qrow = ((size_t)(bl0 + wv * 16 + fr) * BB + b) * DD + h * HDD;
  bf16x8 qf0 = *(const bf16x8*)(qbf + qrow + fg * 8);
  bf16x8 qf1 = *(const bf16x8*)(qbf + qrow + 32 + fg * 8);

  f32x4 o[4];
#pragma unroll
  for (int dt = 0; dt < 4; ++dt) o[dt] = (f32x4){0.f, 0.f, 0.f, 0.f};
  float psum = 0.f;
  char* Pw = Pl + wv * 4096;

  const int p2 = tid >> 3, c8v = tid & 7;
  const size_t vbase = ((size_t)((2 * p2) * BB + b)) * DD + h * HDD + c8v * 8;
  // prologue: ph0 V loads -> regs
  bf16x8 va = *(const bf16x8*)(vbf + vbase);
  bf16x8 vb_ = *(const bf16x8*)(vbf + vbase + BB * DD);

#pragma unroll
  for (int ph = 0; ph < 2; ++ph) {
    if (ph == 1) {
      asm volatile("s_waitcnt lgkmcnt(0)" ::: "memory");
      __builtin_amdgcn_s_barrier();
    }
    // K gll16 first (so counted vmcnt below targets exactly these)
#pragma unroll
    for (int j = 0; j < 2; ++j) {
      int u = tid + j * 512;
      int p = u >> 3, slot = u & 7;
      gll16(kbf + ((size_t)((ph * 128 + p) * BB + b)) * DD + h * HDD +
                8 * (slot ^ (p & 7)),
            Kl + u * 16);
    }
    // V LDS writes from regs
    {
      int pl = (2 * p2) & 63, pc = p2 >> 5;
      char* base = Vt + pc * 8192;
#pragma unroll
      for (int i = 0; i < 8; ++i) {
        int dd = c8v * 8 + i;
        unsigned int packed = (unsigned int)(unsigned short)va[i] |
                              ((unsigned int)(unsigned short)vb_[i] << 16);
        *(unsigned int*)(base + dd * 128 +
            ((((pl >> 3) ^ (dd & 7) ^ (dd >> 3)) & 7) << 4) + ((pl & 7) << 1)) = packed;
      }
    }
    bf16x8 van, vbn;
    if (ph == 0) {   // prefetch ph1 V (rows +128)
      van = *(const bf16x8*)(vbf + vbase + (size_t)128 * BB * DD);
      vbn = *(const bf16x8*)(vbf + vbase + (size_t)129 * BB * DD);
    }
    asm volatile("s_waitcnt lgkmcnt(0)" ::: "memory");
    if (ph == 0) {
      asm volatile("s_waitcnt vmcnt(2)" ::: "memory");   // K done, V-prefetch flying
    } else {
      asm volatile("s_waitcnt vmcnt(0)" ::: "memory");
    }
    __builtin_amdgcn_s_barrier();
    __builtin_amdgcn_sched_barrier(0);

    f32x4 s[8];
    __builtin_amdgcn_s_setprio(1);
#pragma unroll
    for (int pt = 0; pt < 8; ++pt) {
      int pr = pt * 16 + fr;
      bf16x8 a0 = *(const bf16x8*)(Kl + pr * 128 + ((fg ^ (pr & 7)) << 4));
      bf16x8 a1 = *(const bf16x8*)(Kl + pr * 128 + (((4 + fg) ^ (pr & 7)) << 4));
      f32x4 acc = (f32x4){0.f, 0.f, 0.f, 0.f};
      acc = MFMA16(a0, qf0, acc);
      acc = MFMA16(a1, qf1, acc);
      s[pt] = acc;
    }
    __builtin_amdgcn_s_setprio(0);

#pragma unroll
    for (int pt = 0; pt < 8; ++pt) {
      float e0 = __expf(s[pt][0]), e1 = __expf(s[pt][1]);
      float e2 = __expf(s[pt][2]), e3 = __expf(s[pt][3]);
      psum += (e0 + e1) + (e2 + e3);
      uint2 pk2;
      pk2.x = f2bf2(e0, e1);
      pk2.y = f2bf2(e2, e3);
      int pbyte = (pt * 16 + fg * 4) * 2;
      int slot = pbyte >> 4, rem = pbyte & 15;
      *(uint2*)(Pw + fr * 256 + ((slot ^ (fr & 7)) << 4) + rem) = pk2;
    }
    asm volatile("s_waitcnt lgkmcnt(0)" ::: "memory");
    __builtin_amdgcn_sched_barrier(0);

    __builtin_amdgcn_s_setprio(1);
#pragma unroll
    for (int kc = 0; kc < 4; ++kc) {
      int slot = kc * 4 + fg;
      bf16x8 pa = *(const bf16x8*)(Pw + fr * 256 + ((slot ^ (fr & 7)) << 4));
      int sl2 = (kc & 1) * 4 + fg;
#pragma unroll
      for (int dt = 0; dt < 4; ++dt) {
        int dd = dt * 16 + fr;
        bf16x8 vbr = *(const bf16x8*)(Vt + (kc >> 1) * 8192 + dd * 128 +
                     (((sl2 ^ (dd & 7) ^ (dd >> 3)) & 7) << 4));
        o[dt] = MFMA16(pa, vbr, o[dt]);
      }
    }
    __builtin_amdgcn_s_setprio(0);

    if (ph == 0) { va = van; vb_ = vbn; }
  }

  psum += __shfl_xor(psum, 16);
  psum += __shfl_xor(psum, 32);

#pragma unroll
  for (int r = 0; r < 4; ++r) {
    int lloc = fg * 4 + r;
    float inv = 1.f / __shfl(psum, lloc);
    unsigned short* op = attn +
        ((size_t)(bl0 + wv * 16 + lloc) * BB + b) * DD + h * HDD;
#pragma unroll
    for (int dt = 0; dt < 4; ++dt)
      op[dt * 16 + fr] = f2bf(o[dt][r] * inv);
  }
}

extern "C" void kernel_launch(void* const* d_in, const int* in_sizes, int n_in,
                              void* d_out, int out_size, void* d_ws, size_t ws_size,
                              hipStream_t stream) {
  const float* query   = (const float*)d_in[0];
  const float* q_w     = (const float*)d_in[1];
  const float* q_b     = (const float*)d_in[2];
  const float* k_w     = (const float*)d_in[3];
  const float* k_b     = (const float*)d_in[4];
  const float* v_w     = (const float*)d_in[5];
  const float* v_b     = (const float*)d_in[6];
  const float* e_weight= (const float*)d_in[7];
  const float* e_out_w = (const float*)d_in[8];
  const float* e_out_b = (const float*)d_in[9];
  const float* ln_g    = (const float*)d_in[10];
  const float* ln_b    = (const float*)d_in[11];
  const float* out_w   = (const float*)d_in[12];
  const float* out_b   = (const float*)d_in[13];
  float* out = (float*)d_out;

  char* w = (char*)d_ws;
  unsigned short* parts   = (unsigned short*)w;                 // 16 MB, dead after reduce
  unsigned short* q_bf    = (unsigned short*)w;                 // 32 MB (alias, after reduce)
  unsigned short* attn_bf = (unsigned short*)(w + (32u << 20)); // 32 MB
  unsigned short* query_bf= (unsigned short*)(w + (64u << 20)); // 32 MB
  unsigned short* kv_raw  = (unsigned short*)(w + (96u << 20)); // 2 MB
  float* kv_eo            = (float*)(w + (98u << 20));          // 4 MB
  unsigned short* kv_ln   = (unsigned short*)(w + (102u << 20));// 2 MB
  unsigned short* k_buf   = (unsigned short*)(w + (104u << 20));// 2 MB
  unsigned short* v_buf   = (unsigned short*)(w + (106u << 20));// 2 MB
  unsigned short* wq  = (unsigned short*)(w + (108u << 20));
  unsigned short* wk  = (unsigned short*)(w + (110u << 20));
  unsigned short* wv_ = (unsigned short*)(w + (112u << 20));
  unsigned short* weo = (unsigned short*)(w + (114u << 20));
  unsigned short* wo  = (unsigned short*)(w + (116u << 20));
  unsigned short* ewb = (unsigned short*)(w + (118u << 20));    // 0.5 MB

  k_cvt_w<<<2688, 256, 0, stream>>>(q_w, k_w, v_w, e_out_w, out_w, e_weight,
                                    wq, wk, wv_, weo, wo, ewb);

  k_compress_mfma<<<dim3(64, LC), 256, 0, stream>>>(query, ewb, query_bf, parts);
  k_reduce<<<512, 256, 0, stream>>>(parts, kv_raw);
  k_gemm_mfma<2, float><<<dim3(8, 8), 256, 0, stream>>>(kv_raw, weo, e_out_b, e_weight, kv_eo);
  k_ln<<<PP * BB, 256, 0, stream>>>(kv_eo, ln_g, ln_b, kv_ln);
  k_gemm256<1, unsigned short><<<dim3(64, 4), 512, 0, stream>>>(query_bf, wq, q_b, q_bf);
  k_gemm_kv<<<dim3(8, 8, 2), 256, 0, stream>>>(kv_ln, wk, wv_, k_b, v_b, k_buf, v_buf);
  k_attn_mfma<<<dim3(32, 64), 512, 0, stream>>>(q_bf, k_buf, v_buf, attn_bf);
  k_gemm256<0, float><<<dim3(64, 4), 512, 0, stream>>>(attn_bf, wo, out_b, out);
}